// Round 3
// baseline (162.267 us; speedup 1.0000x reference)
//
#include <hip/hip_runtime.h>
#include <hip/hip_bf16.h>

// MultiHeadAttentionLegacy: B=2, S=2048, E=768, H=12, HD=64, G=B*H=24
// Inputs fp32, output fp32; internal bf16 MFMA pipeline.
// Legacy reshape = pure flat re-chunk: [4096][768] buffer == 24 slabs [2048][64].
// Softmax denominator over FULL row; tril mask applied AFTER softmax.
// Q projection pre-scaled by log2(e)/sqrt(64) so attention uses exp2 directly.
//
// R1: pre-convert q/k/v fp32->bf16 so the QKV GEMM uses fire-and-forget
// global_load_lds for both operands (was: mid-loop fp32 load+cvt stall).
// R2 (FAILED, reverted): deeper LDS pipeline made attn worse -> not latency-bound.
// R3: attn K/V is L2-resident (3 groups/XCD = 1.5MB of 4MB by the XCD swizzle),
// so LDS staging + barriers + vmcnt were pure overhead (m169 lesson). Main loop
// now reads K/V fragments straight from global into registers, software-pipelined
// one chunk ahead; zero barriers, zero LDS in the loop. Active-prefix /
// denominator-tail loop split removes per-iter masking branches.

typedef __bf16 bf16;
typedef __attribute__((ext_vector_type(4))) __bf16 bf16x4;
typedef __attribute__((ext_vector_type(8))) __bf16 bf16x8;
typedef __attribute__((ext_vector_type(4))) float f32x4;
typedef __attribute__((ext_vector_type(16))) float f32x16;
typedef __attribute__((ext_vector_type(4))) unsigned int uint4v;

#define MFMA16(a,b,c) __builtin_amdgcn_mfma_f32_16x16x32_bf16((a),(b),(c),0,0,0)
#define MFMA32(a,b,c) __builtin_amdgcn_mfma_f32_32x32x16_bf16((a),(b),(c),0,0,0)

typedef const __attribute__((address_space(1))) unsigned int GU32;
typedef __attribute__((address_space(3))) unsigned int LU32;

__device__ __forceinline__ void gll16(const void* gsrc, void* ldst) {
    __builtin_amdgcn_global_load_lds((GU32*)gsrc, (LU32*)ldst, 16, 0, 0);
}

__device__ __forceinline__ unsigned pk_bf16(float lo, float hi) {
    unsigned r;
    asm("v_cvt_pk_bf16_f32 %0, %1, %2" : "=v"(r) : "v"(lo), "v"(hi));
    return r;
}

// v_permlane32_swap_b32: a.hi32lanes <-> b.lo32lanes
__device__ __forceinline__ void plane32swap(unsigned &a, unsigned &b) {
    asm("v_permlane32_swap_b32 %0, %1" : "+v"(a), "+v"(b));
}

__device__ __forceinline__ bf16x8 frag_words(unsigned w0, unsigned w1, unsigned w2, unsigned w3) {
    union { unsigned u[4]; bf16x8 v; } f;
    f.u[0] = w0; f.u[1] = w1; f.u[2] = w2; f.u[3] = w3;
    return f.v;
}

// ------- fp32 -> bf16 streaming convert for q/k/v activations -------
__global__ __launch_bounds__(256) void cvt_qkv(
    const float* __restrict__ q, const float* __restrict__ k, const float* __restrict__ v,
    bf16* __restrict__ Qb, bf16* __restrict__ Kb, bf16* __restrict__ Vb)
{
    const float* src = blockIdx.y == 0 ? q : blockIdx.y == 1 ? k : v;
    bf16* dst = blockIdx.y == 0 ? Qb : blockIdx.y == 1 ? Kb : Vb;
    const size_t base = (size_t)blockIdx.x * 2048 + (size_t)threadIdx.x * 8;
    f32x4 lo = *(const f32x4*)&src[base];
    f32x4 hi = *(const f32x4*)&src[base + 4];
    bf16x8 o;
    for (int j = 0; j < 4; ++j) { o[j] = (bf16)lo[j]; o[4 + j] = (bf16)hi[j]; }
    *(bf16x8*)&dst[base] = o;
}

// ------- weight transpose + cvt: out_bf16[n*768+k] = (bf16)in_f32[k*768+n] -------
struct TArg { const float* in; bf16* out; };

__global__ __launch_bounds__(256) void transpose_w(TArg a0, TArg a1, TArg a2, TArg a3) {
    TArg ta = blockIdx.z == 0 ? a0 : blockIdx.z == 1 ? a1 : blockIdx.z == 2 ? a2 : a3;
    __shared__ bf16 tile[64][72];
    const int bx = blockIdx.x % 12, by = blockIdx.x / 12;
    const int k0 = by * 64, n0 = bx * 64;
    const int tid = threadIdx.x;
    for (int q = 0; q < 2; ++q) {
        int idx = q * 256 + tid;
        int i = idx >> 3, j0 = (idx & 7) * 8;
        const float* src = &ta.in[(size_t)(k0 + i) * 768 + n0 + j0];
        f32x4 lo = *(const f32x4*)&src[0];
        f32x4 hi = *(const f32x4*)&src[4];
        bf16x8 v;
        for (int j = 0; j < 4; ++j) { v[j] = (bf16)lo[j]; v[4 + j] = (bf16)hi[j]; }
        *(bf16x8*)&tile[i][j0] = v;
    }
    __syncthreads();
    for (int q = 0; q < 2; ++q) {
        int idx = q * 256 + tid;
        int n = idx >> 3, j0 = (idx & 7) * 8;
        bf16x8 v;
        for (int jj = 0; jj < 8; ++jj) v[jj] = tile[j0 + jj][n];
        *(bf16x8*)&ta.out[(size_t)(n0 + n) * 768 + k0 + j0] = v;
    }
}

// ------- V slab transpose: Vt[g][d][k] = Vp[g*131072 + k*64 + d] -------
__global__ __launch_bounds__(256) void vtrans(const bf16* __restrict__ Vp, bf16* __restrict__ Vt) {
    __shared__ bf16 tile[64][72];
    const int g = blockIdx.y;
    const int k0 = blockIdx.x * 64;
    const bf16* src = Vp + (size_t)g * 131072;
    bf16* dst = Vt + (size_t)g * 131072;
    const int tid = threadIdx.x;
    for (int q = 0; q < 2; ++q) {
        int idx = q * 256 + tid;
        int r = idx >> 3, c = (idx & 7) * 8;
        *(uint4v*)&tile[r][c] = *(const uint4v*)&src[(size_t)(k0 + r) * 64 + c];
    }
    __syncthreads();
    for (int q = 0; q < 2; ++q) {
        int idx = q * 256 + tid;
        int d = idx >> 3, c = (idx & 7) * 8;
        bf16x8 v;
        for (int j = 0; j < 8; ++j) v[j] = tile[c + j][d];
        *(bf16x8*)&dst[(size_t)d * 2048 + k0 + c] = v;
    }
}

// --- GEMM: C[4096x768] = (A @ Bt^T + bias) * scale.  A is bf16 always.
//     MODE 0: C bf16 (proj);  MODE 1: C fp32 (out) ---
struct GArg { const bf16* A; const bf16* Bt; const float* bias; void* C; float scale; };

template<int MODE>
__global__ __launch_bounds__(256) void gemm_bt_bias(GArg g0, GArg g1, GArg g2) {
    GArg ga = blockIdx.z == 0 ? g0 : blockIdx.z == 1 ? g1 : g2;
    const int K = 768, N = 768;
    __shared__ bf16 As[2][128][64];
    __shared__ bf16 Bs[2][128][64];
    const int tid = threadIdx.x;
    const int lane = tid & 63, wave = tid >> 6;
    const int l15 = lane & 15, lg = lane >> 4;
    const int r0 = blockIdx.y * 128, c0 = blockIdx.x * 128;
    const int wr = (wave >> 1) * 64, wc = (wave & 1) * 64;
    f32x4 acc[4][4] = {};

    const int grow = wave * 8 + (lane >> 3);
    const int gcol = 8 * ((lane & 7) ^ (lane >> 3));

    auto stage = [&](int kt, int buf) {
        for (int i = 0; i < 4; ++i)
            gll16(&ga.A[(size_t)(r0 + i * 32 + grow) * K + kt + gcol], &As[buf][i * 32 + wave * 8][0]);
        for (int i = 0; i < 4; ++i)
            gll16(&ga.Bt[(size_t)(c0 + i * 32 + grow) * K + kt + gcol], &Bs[buf][i * 32 + wave * 8][0]);
    };

    stage(0, 0);
    __syncthreads();

    for (int c = 0; c < 12; ++c) {
        const int buf = c & 1;
        if (c < 11) stage((c + 1) * 64, buf ^ 1);   // fire-and-forget, drained at barrier
        for (int kk = 0; kk < 2; ++kk) {
            bf16x8 af[4], bfr[4];
            for (int i = 0; i < 4; ++i) {
                int row = wr + i * 16 + l15;
                af[i] = *(const bf16x8*)&As[buf][row][(kk * 32 + lg * 8) ^ ((row & 7) * 8)];
            }
            for (int j = 0; j < 4; ++j) {
                int row = wc + j * 16 + l15;
                bfr[j] = *(const bf16x8*)&Bs[buf][row][(kk * 32 + lg * 8) ^ ((row & 7) * 8)];
            }
            __builtin_amdgcn_s_setprio(1);
            for (int i = 0; i < 4; ++i)
                for (int j = 0; j < 4; ++j)
                    acc[i][j] = MFMA16(af[i], bfr[j], acc[i][j]);
            __builtin_amdgcn_s_setprio(0);
        }
        __syncthreads();
    }
    for (int j = 0; j < 4; ++j) {
        int col = c0 + wc + j * 16 + l15;
        float bv = ga.bias[col];
        for (int i = 0; i < 4; ++i) {
            int row = r0 + wr + i * 16 + lg * 4;
            for (int r = 0; r < 4; ++r) {
                float val = (acc[i][j][r] + bv) * ga.scale;
                if constexpr (MODE == 0)
                    ((bf16*)ga.C)[(size_t)(row + r) * N + col] = (bf16)val;
                else
                    ((float*)ga.C)[(size_t)(row + r) * N + col] = val;
            }
        }
    }
}

// ------- attention v7: barrier-free, register-resident K/V from L2 -------
// Block = 4 waves over 64 q-rows. Wave (wq=w>>1, p=w&1): q rows t0+wq*32..+31,
// k-half p of each 64-chunk. Swapped QK: S-regs q=lane&31, k=(r&3)+8*(r>>2)+4*hi.
// K/V read directly from global (L2-resident per XCD) as per-lane 16B fragments,
// software-pipelined one chunk ahead. No LDS / barriers / waitcnt in main loop.
// Loop split: active prefix (QK+softmax+PV) then denominator-only tail (QK+exp2).
// Cross-pair O/denom reduce via small dedicated LDS at the end (one barrier).
__global__ __launch_bounds__(256, 3) void attn_kernel(
    const bf16* __restrict__ Qp, const bf16* __restrict__ Kp,
    const bf16* __restrict__ Vtg, bf16* __restrict__ Ob)
{
    // XCD swizzle: 768 blocks = 8 XCDs x 96; 96 = 3 whole groups -> L2-local K/V
    const int bid = blockIdx.x;
    const int wg = (bid & 7) * 96 + (bid >> 3);
    const int g = wg >> 5, bx = wg & 31;
    const int t0 = bx * 64;
    const int tid = threadIdx.x, lane = tid & 63, w = tid >> 6;
    const int wq = w >> 1, p = w & 1;
    const int l31 = lane & 31, hi = lane >> 5;

    __shared__ float Ored[2][32][64];   // [wq][q][d] partials from p==1 waves
    __shared__ float dred[4][32];       // [wave][q] denominators

    const bf16* Qg = Qp + (size_t)g * 131072;
    const bf16* Kg = Kp + (size_t)g * 131072;
    const bf16* Vg = Vtg + (size_t)g * 131072;   // [64][2048]
    bf16* Og = Ob + (size_t)g * 131072;

    // Q B-frags in registers: col=q=l31, k-dim d = m*16 + hi*8 + j
    const int qrow = t0 + wq * 32 + l31;
    bf16x8 qB[4];
    for (int m = 0; m < 4; ++m)
        qB[m] = *(const bf16x8*)&Qg[(size_t)qrow * 64 + m * 16 + hi * 8];

    const int qmin = t0 + wq * 32, qmax = qmin + 31;   // wave's q range
    const int kofs = p * 32;                            // wave's k-half offset
    // active chunks = prefix [0, nact)
    const int nact = (qmax - kofs + 64) >> 6;

    // per-lane fragment pointers (chunk c: kptr + c*4096, v*ptr + c*64)
    const bf16* kptr  = &Kg[(size_t)(kofs + l31) * 64 + hi * 8];
    const bf16* v0ptr = &Vg[(size_t)l31 * 2048 + kofs + hi * 8];
    const bf16* v1ptr = v0ptr + 32 * 2048;

    // prologue: chunk 0 fragments
    bf16x8 kf[4], vf0[2], vf1[2];
    for (int m = 0; m < 4; ++m) kf[m] = *(const bf16x8*)&kptr[m * 16];
    for (int kt = 0; kt < 2; ++kt) {
        vf0[kt] = *(const bf16x8*)&v0ptr[kt * 16];
        vf1[kt] = *(const bf16x8*)&v1ptr[kt * 16];
    }

    f32x16 oacc0 = {}, oacc1 = {};
    float dsum = 0.f;

    // ---- active prefix: QK + softmax + PV ----
    for (int c = 0; c < nact; ++c) {
        const int kc = c * 64;
        const bool fullc = (kc + kofs + 31 <= qmin);    // wave-uniform

        f32x16 s = {};
        __builtin_amdgcn_s_setprio(1);
        for (int m = 0; m < 4; ++m) s = MFMA32(kf[m], qB[m], s);
        __builtin_amdgcn_s_setprio(0);

        // prefetch next chunk's K fragments (WAR on kf after MFMA reads)
        if (c < 31) {
            const bf16* kn = kptr + (size_t)(c + 1) * 4096;
            for (int m = 0; m < 4; ++m) kf[m] = *(const bf16x8*)&kn[m * 16];
        }

        // exp2 (Q pre-scaled by log2e/8) + denominator (UNmasked, tree sum)
        float e[16];
        for (int r = 0; r < 16; ++r) e[r] = __builtin_exp2f(s[r]);
        {
            float p01 = e[0] + e[1],  p23 = e[2] + e[3];
            float p45 = e[4] + e[5],  p67 = e[6] + e[7];
            float p89 = e[8] + e[9],  pab = e[10] + e[11];
            float pcd = e[12] + e[13], pef = e[14] + e[15];
            float q0 = p01 + p23, q1 = p45 + p67, q2 = p89 + pab, q3 = pcd + pef;
            dsum += (q0 + q1) + (q2 + q3);
        }

        if (!fullc) {   // diagonal: tril AFTER softmax
            for (int r = 0; r < 16; ++r) {
                int kg = kc + kofs + (r & 3) + 8 * (r >> 2) + 4 * hi;
                if (kg > qrow) e[r] = 0.f;
            }
        }
        // pack P to bf16 + permlane32_swap -> 2 PV A-frags
        bf16x8 pf[2];
        {
            unsigned a0 = pk_bf16(e[0], e[1]), a1 = pk_bf16(e[2], e[3]);
            unsigned b0 = pk_bf16(e[4], e[5]), b1 = pk_bf16(e[6], e[7]);
            plane32swap(a0, b0); plane32swap(a1, b1);
            pf[0] = frag_words(a0, a1, b0, b1);
            a0 = pk_bf16(e[8], e[9]);   a1 = pk_bf16(e[10], e[11]);
            b0 = pk_bf16(e[12], e[13]); b1 = pk_bf16(e[14], e[15]);
            plane32swap(a0, b0); plane32swap(a1, b1);
            pf[1] = frag_words(a0, a1, b0, b1);
        }
        // PV: A = P frags, B = V^T fragments (col d, row k)
        __builtin_amdgcn_s_setprio(1);
        for (int kt = 0; kt < 2; ++kt) {
            oacc0 = MFMA32(pf[kt], vf0[kt], oacc0);
            oacc1 = MFMA32(pf[kt], vf1[kt], oacc1);
        }
        __builtin_amdgcn_s_setprio(0);

        // prefetch next chunk's V fragments (only if next chunk is active)
        if (c + 1 < nact) {
            const bf16* vn0 = v0ptr + (size_t)(c + 1) * 64;
            const bf16* vn1 = v1ptr + (size_t)(c + 1) * 64;
            for (int kt = 0; kt < 2; ++kt) {
                vf0[kt] = *(const bf16x8*)&vn0[kt * 16];
                vf1[kt] = *(const bf16x8*)&vn1[kt * 16];
            }
        }
    }

    // ---- denominator-only tail: QK + exp2 + sum ----
    for (int c = nact; c < 32; ++c) {
        f32x16 s = {};
        __builtin_amdgcn_s_setprio(1);
        for (int m = 0; m < 4; ++m) s = MFMA32(kf[m], qB[m], s);
        __builtin_amdgcn_s_setprio(0);

        if (c < 31) {
            const bf16* kn = kptr + (size_t)(c + 1) * 4096;
            for (int m = 0; m < 4; ++m) kf[m] = *(const bf16x8*)&kn[m * 16];
        }

        float e[16];
        for (int r = 0; r < 16; ++r) e[r] = __builtin_exp2f(s[r]);
        {
            float p01 = e[0] + e[1],  p23 = e[2] + e[3];
            float p45 = e[4] + e[5],  p67 = e[6] + e[7];
            float p89 = e[8] + e[9],  pab = e[10] + e[11];
            float pcd = e[12] + e[13], pef = e[14] + e[15];
            float q0 = p01 + p23, q1 = p45 + p67, q2 = p89 + pab, q3 = pcd + pef;
            dsum += (q0 + q1) + (q2 + q3);
        }
    }

    // ---- wave-internal k reduce: lane & lane^32 hold complementary k for q=l31
    dsum += __shfl_xor(dsum, 32);

    // ---- cross-pair reduce (each wave writes its own region; one barrier)
    if (lane < 32) dred[w][l31] = dsum;
    if (p == 1) {
        for (int r = 0; r < 16; ++r) {
            const int qoff = (r & 3) + 8 * (r >> 2) + 4 * hi;
            Ored[wq][qoff][l31]      = oacc0[r];
            Ored[wq][qoff][32 + l31] = oacc1[r];
        }
    }
    __syncthreads();
    if (p == 0) {
        const float dtot = dsum + dred[w + 1][l31];
        const float rall = 1.0f / dtot;          // valid for q=l31 at every lane
        for (int r = 0; r < 16; ++r) {
            const int qoff = (r & 3) + 8 * (r >> 2) + 4 * hi;
            const float inv = __shfl(rall, qoff);
            const size_t row = (size_t)(t0 + wq * 32 + qoff) * 64;
            Og[row + l31]      = (bf16)((oacc0[r] + Ored[wq][qoff][l31])      * inv);
            Og[row + 32 + l31] = (bf16)((oacc1[r] + Ored[wq][qoff][32 + l31]) * inv);
        }
    }
}

// ---------------- host ----------------
extern "C" void kernel_launch(void* const* d_in, const int* in_sizes, int n_in,
                              void* d_out, int out_size, void* d_ws, size_t ws_size,
                              hipStream_t stream) {
    const float* query = (const float*)d_in[0];
    const float* key_  = (const float*)d_in[1];
    const float* value = (const float*)d_in[2];
    const float* Wq = (const float*)d_in[3];
    const float* bq = (const float*)d_in[4];
    const float* Wk = (const float*)d_in[5];
    const float* bk = (const float*)d_in[6];
    const float* Wv = (const float*)d_in[7];
    const float* bv = (const float*)d_in[8];
    const float* Wo = (const float*)d_in[9];
    const float* bo = (const float*)d_in[10];
    float* out = (float*)d_out;

    const size_t MN = (size_t)4096 * 768;
    const size_t WW = (size_t)768 * 768;
    bf16* Qp  = (bf16*)d_ws;
    bf16* Kp  = Qp + MN;
    bf16* Vp  = Kp + MN;
    bf16* Obf = Vp + MN;
    bf16* Vtg = Obf + MN;
    bf16* WtQ = Vtg + MN;
    bf16* WtK = WtQ + WW;
    bf16* WtV = WtK + WW;
    bf16* WtO = WtV + WW;
    bf16* Vb  = WtO + WW;    // +1 MN slab
    // bf16 activation inputs: Qb/Kb alias slabs that are only written later
    // (Obf by attn, Vtg by vtrans) — both dead until after gemm<0> consumes them.
    bf16* Qb  = Obf;
    bf16* Kb  = Vtg;

    cvt_qkv<<<dim3(1536, 3), 256, 0, stream>>>(query, key_, value, Qb, Kb, Vb);

    transpose_w<<<dim3(144, 1, 4), 256, 0, stream>>>(
        TArg{Wq, WtQ}, TArg{Wk, WtK}, TArg{Wv, WtV}, TArg{Wo, WtO});

    // fold log2(e)/sqrt(HD) into Q so attention uses native exp2
    gemm_bt_bias<0><<<dim3(6, 32, 3), 256, 0, stream>>>(
        GArg{Qb, WtQ, bq, Qp, 0.18033688f},
        GArg{Kb, WtK, bk, Kp, 1.0f},
        GArg{Vb, WtV, bv, Vp, 1.0f});

    vtrans<<<dim3(32, 24), 256, 0, stream>>>(Vp, Vtg);

    attn_kernel<<<dim3(768), 256, 0, stream>>>(Qp, Kp, Vtg, Obf);

    gemm_bt_bias<1><<<dim3(6, 32, 1), 256, 0, stream>>>(
        GArg{Obf, WtO, bo, out, 1.0f},
        GArg{Obf, WtO, bo, out, 1.0f},
        GArg{Obf, WtO, bo, out, 1.0f});
}

// Round 4
// 123.326 us; speedup vs baseline: 1.3158x; 1.3158x over previous
//
#include <hip/hip_runtime.h>
#include <hip/hip_bf16.h>

// MultiHeadAttentionLegacy: B=2, S=2048, E=768, H=12, HD=64, G=B*H=24
// Inputs fp32, output fp32; internal bf16 MFMA pipeline.
// Legacy reshape = pure flat re-chunk: [4096][768] buffer == 24 slabs [2048][64].
// Softmax denominator over FULL row; tril mask applied AFTER softmax.
// Q projection pre-scaled by log2(e)/sqrt(64) so attention uses exp2 directly.
//
// R1: pre-convert q/k/v fp32->bf16 so the QKV GEMM uses fire-and-forget
// global_load_lds for both operands (was: mid-loop fp32 load+cvt stall).
// R2 (FAILED): deeper LDS pipeline -> worse. Not memory-latency-bound.
// R3 (FAILED): direct per-lane L2 reads -> 2x worse. Each wave privately
// re-read K/V => L1 request path saturated. LDS staging is the right call.
// R4: back to the v5 (55.6us) LDS structure; cut ROUND COUNT instead.
// Chunks past the diagonal are denominator-only (QK+exp2, no V/PV/pack);
// process those two-K-chunks-per-round, staging the 2nd chunk in the idle
// V buffer. Rounds: 32 -> nc + ceil((32-nc)/2)  (avg ~24.5/block, -23%).

typedef __bf16 bf16;
typedef __attribute__((ext_vector_type(4))) __bf16 bf16x4;
typedef __attribute__((ext_vector_type(8))) __bf16 bf16x8;
typedef __attribute__((ext_vector_type(4))) float f32x4;
typedef __attribute__((ext_vector_type(16))) float f32x16;
typedef __attribute__((ext_vector_type(4))) unsigned int uint4v;

#define MFMA16(a,b,c) __builtin_amdgcn_mfma_f32_16x16x32_bf16((a),(b),(c),0,0,0)
#define MFMA32(a,b,c) __builtin_amdgcn_mfma_f32_32x32x16_bf16((a),(b),(c),0,0,0)

typedef const __attribute__((address_space(1))) unsigned int GU32;
typedef __attribute__((address_space(3))) unsigned int LU32;

__device__ __forceinline__ void gll16(const void* gsrc, void* ldst) {
    __builtin_amdgcn_global_load_lds((GU32*)gsrc, (LU32*)ldst, 16, 0, 0);
}

__device__ __forceinline__ unsigned pk_bf16(float lo, float hi) {
    unsigned r;
    asm("v_cvt_pk_bf16_f32 %0, %1, %2" : "=v"(r) : "v"(lo), "v"(hi));
    return r;
}

// v_permlane32_swap_b32: a.hi32lanes <-> b.lo32lanes
__device__ __forceinline__ void plane32swap(unsigned &a, unsigned &b) {
    asm("v_permlane32_swap_b32 %0, %1" : "+v"(a), "+v"(b));
}

__device__ __forceinline__ bf16x8 frag_words(unsigned w0, unsigned w1, unsigned w2, unsigned w3) {
    union { unsigned u[4]; bf16x8 v; } f;
    f.u[0] = w0; f.u[1] = w1; f.u[2] = w2; f.u[3] = w3;
    return f.v;
}

// ------- fp32 -> bf16 streaming convert for q/k/v activations -------
__global__ __launch_bounds__(256) void cvt_qkv(
    const float* __restrict__ q, const float* __restrict__ k, const float* __restrict__ v,
    bf16* __restrict__ Qb, bf16* __restrict__ Kb, bf16* __restrict__ Vb)
{
    const float* src = blockIdx.y == 0 ? q : blockIdx.y == 1 ? k : v;
    bf16* dst = blockIdx.y == 0 ? Qb : blockIdx.y == 1 ? Kb : Vb;
    const size_t base = (size_t)blockIdx.x * 2048 + (size_t)threadIdx.x * 8;
    f32x4 lo = *(const f32x4*)&src[base];
    f32x4 hi = *(const f32x4*)&src[base + 4];
    bf16x8 o;
    for (int j = 0; j < 4; ++j) { o[j] = (bf16)lo[j]; o[4 + j] = (bf16)hi[j]; }
    *(bf16x8*)&dst[base] = o;
}

// ------- weight transpose + cvt: out_bf16[n*768+k] = (bf16)in_f32[k*768+n] -------
struct TArg { const float* in; bf16* out; };

__global__ __launch_bounds__(256) void transpose_w(TArg a0, TArg a1, TArg a2, TArg a3) {
    TArg ta = blockIdx.z == 0 ? a0 : blockIdx.z == 1 ? a1 : blockIdx.z == 2 ? a2 : a3;
    __shared__ bf16 tile[64][72];
    const int bx = blockIdx.x % 12, by = blockIdx.x / 12;
    const int k0 = by * 64, n0 = bx * 64;
    const int tid = threadIdx.x;
    for (int q = 0; q < 2; ++q) {
        int idx = q * 256 + tid;
        int i = idx >> 3, j0 = (idx & 7) * 8;
        const float* src = &ta.in[(size_t)(k0 + i) * 768 + n0 + j0];
        f32x4 lo = *(const f32x4*)&src[0];
        f32x4 hi = *(const f32x4*)&src[4];
        bf16x8 v;
        for (int j = 0; j < 4; ++j) { v[j] = (bf16)lo[j]; v[4 + j] = (bf16)hi[j]; }
        *(bf16x8*)&tile[i][j0] = v;
    }
    __syncthreads();
    for (int q = 0; q < 2; ++q) {
        int idx = q * 256 + tid;
        int n = idx >> 3, j0 = (idx & 7) * 8;
        bf16x8 v;
        for (int jj = 0; jj < 8; ++jj) v[jj] = tile[j0 + jj][n];
        *(bf16x8*)&ta.out[(size_t)(n0 + n) * 768 + k0 + j0] = v;
    }
}

// ------- V slab transpose: Vt[g][d][k] = Vp[g*131072 + k*64 + d] -------
__global__ __launch_bounds__(256) void vtrans(const bf16* __restrict__ Vp, bf16* __restrict__ Vt) {
    __shared__ bf16 tile[64][72];
    const int g = blockIdx.y;
    const int k0 = blockIdx.x * 64;
    const bf16* src = Vp + (size_t)g * 131072;
    bf16* dst = Vt + (size_t)g * 131072;
    const int tid = threadIdx.x;
    for (int q = 0; q < 2; ++q) {
        int idx = q * 256 + tid;
        int r = idx >> 3, c = (idx & 7) * 8;
        *(uint4v*)&tile[r][c] = *(const uint4v*)&src[(size_t)(k0 + r) * 64 + c];
    }
    __syncthreads();
    for (int q = 0; q < 2; ++q) {
        int idx = q * 256 + tid;
        int d = idx >> 3, c = (idx & 7) * 8;
        bf16x8 v;
        for (int j = 0; j < 8; ++j) v[j] = tile[c + j][d];
        *(bf16x8*)&dst[(size_t)d * 2048 + k0 + c] = v;
    }
}

// --- GEMM: C[4096x768] = (A @ Bt^T + bias) * scale.  A is bf16 always.
//     MODE 0: C bf16 (proj);  MODE 1: C fp32 (out) ---
struct GArg { const bf16* A; const bf16* Bt; const float* bias; void* C; float scale; };

template<int MODE>
__global__ __launch_bounds__(256) void gemm_bt_bias(GArg g0, GArg g1, GArg g2) {
    GArg ga = blockIdx.z == 0 ? g0 : blockIdx.z == 1 ? g1 : g2;
    const int K = 768, N = 768;
    __shared__ bf16 As[2][128][64];
    __shared__ bf16 Bs[2][128][64];
    const int tid = threadIdx.x;
    const int lane = tid & 63, wave = tid >> 6;
    const int l15 = lane & 15, lg = lane >> 4;
    const int r0 = blockIdx.y * 128, c0 = blockIdx.x * 128;
    const int wr = (wave >> 1) * 64, wc = (wave & 1) * 64;
    f32x4 acc[4][4] = {};

    const int grow = wave * 8 + (lane >> 3);
    const int gcol = 8 * ((lane & 7) ^ (lane >> 3));

    auto stage = [&](int kt, int buf) {
        for (int i = 0; i < 4; ++i)
            gll16(&ga.A[(size_t)(r0 + i * 32 + grow) * K + kt + gcol], &As[buf][i * 32 + wave * 8][0]);
        for (int i = 0; i < 4; ++i)
            gll16(&ga.Bt[(size_t)(c0 + i * 32 + grow) * K + kt + gcol], &Bs[buf][i * 32 + wave * 8][0]);
    };

    stage(0, 0);
    __syncthreads();

    for (int c = 0; c < 12; ++c) {
        const int buf = c & 1;
        if (c < 11) stage((c + 1) * 64, buf ^ 1);   // fire-and-forget, drained at barrier
        for (int kk = 0; kk < 2; ++kk) {
            bf16x8 af[4], bfr[4];
            for (int i = 0; i < 4; ++i) {
                int row = wr + i * 16 + l15;
                af[i] = *(const bf16x8*)&As[buf][row][(kk * 32 + lg * 8) ^ ((row & 7) * 8)];
            }
            for (int j = 0; j < 4; ++j) {
                int row = wc + j * 16 + l15;
                bfr[j] = *(const bf16x8*)&Bs[buf][row][(kk * 32 + lg * 8) ^ ((row & 7) * 8)];
            }
            __builtin_amdgcn_s_setprio(1);
            for (int i = 0; i < 4; ++i)
                for (int j = 0; j < 4; ++j)
                    acc[i][j] = MFMA16(af[i], bfr[j], acc[i][j]);
            __builtin_amdgcn_s_setprio(0);
        }
        __syncthreads();
    }
    for (int j = 0; j < 4; ++j) {
        int col = c0 + wc + j * 16 + l15;
        float bv = ga.bias[col];
        for (int i = 0; i < 4; ++i) {
            int row = r0 + wr + i * 16 + lg * 4;
            for (int r = 0; r < 4; ++r) {
                float val = (acc[i][j][r] + bv) * ga.scale;
                if constexpr (MODE == 0)
                    ((bf16*)ga.C)[(size_t)(row + r) * N + col] = (bf16)val;
                else
                    ((float*)ga.C)[(size_t)(row + r) * N + col] = val;
            }
        }
    }
}

// ------- attention v8: v5 LDS structure + paired denominator tail -------
// Block = 4 waves over 64 q-rows. Wave (wq=w>>1, p=w&1): q rows t0+wq*32..+31,
// k-half p of each 64-chunk. Swapped QK: S-regs q=lane&31, k=(r&3)+8*(r>>2)+4*hi.
// Causal loop: chunks [0, nc) with K+V staged, QK+softmax+PV.
// Tail loop: chunks [nc, 32) two per round, 2nd K chunk staged in the V buffer;
// QK+exp2+sum only. First tail pair staged by the last causal iteration (the
// buf^1 halves are dead there) -> no transition bubble.
__global__ __launch_bounds__(256) void attn_kernel(
    const bf16* __restrict__ Qp, const bf16* __restrict__ Kp,
    const bf16* __restrict__ Vtg, bf16* __restrict__ Ob)
{
    // XCD swizzle: 768 blocks = 8 XCDs x 96; 96 = 3 whole groups -> L2-local K/V
    const int bid = blockIdx.x;
    const int wg = (bid & 7) * 96 + (bid >> 3);
    const int g = wg >> 5, bx = wg & 31;
    const int t0 = bx * 64;
    const int tid = threadIdx.x, lane = tid & 63, w = tid >> 6;
    const int wq = w >> 1, p = w & 1;
    const int l31 = lane & 31, hi = lane >> 5;

    __shared__ __align__(16) char smem[32768];
    bf16 (*Ks)[64][64] = (bf16(*)[64][64])smem;             // [2][k][d], d-swizzled
    bf16 (*Vs)[64][64] = (bf16(*)[64][64])(smem + 16384);   // [2][d][k] causal / 2nd K chunk in tail

    const bf16* Qg = Qp + (size_t)g * 131072;
    const bf16* Kg = Kp + (size_t)g * 131072;
    const bf16* Vg = Vtg + (size_t)g * 131072;   // [64][2048]
    bf16* Og = Ob + (size_t)g * 131072;

    // Q B-frags in registers: col=q=l31, k-dim d = m*16 + hi*8 + j
    const int qrow = t0 + wq * 32 + l31;
    bf16x8 qB[4];
    for (int m = 0; m < 4; ++m)
        qB[m] = *(const bf16x8*)&Qg[(size_t)qrow * 64 + m * 16 + hi * 8];

    // staging: wave stages 16 rows (2 gll of 8 rows), pre-swizzled source col
    const int srow = w * 16 + (lane >> 3);
    const int scol = 8 * ((lane & 7) ^ (lane >> 3));
    auto stageKto = [&](int ch, bf16 (*dst)[64]) {
        const bf16* src = &Kg[(size_t)(ch * 64 + srow) * 64 + scol];
        gll16(src, &dst[w * 16][0]);
        gll16(src + 8 * 64, &dst[w * 16 + 8][0]);
    };
    auto stageVto = [&](int ch, bf16 (*dst)[64]) {
        const bf16* src = &Vg[(size_t)srow * 2048 + ch * 64 + scol];
        gll16(src, &dst[w * 16][0]);
        gll16(src + 8 * 2048, &dst[w * 16 + 8][0]);
    };

    stageKto(0, Ks[0]);
    stageVto(0, Vs[0]);

    f32x16 oacc0 = {}, oacc1 = {};
    float dsum = 0.f;
    const int qmin = t0 + wq * 32, qmax = qmin + 31;   // wave's q range
    const int kofs = p * 32;                            // wave's k-half offset
    const int swz = (l31 & 7) * 8;
    const int nc = bx + 1;                              // causal chunk count (block-uniform)

    // ---- causal loop: QK + softmax + PV ----
    for (int c = 0; c < nc; ++c) {
        const int buf = c & 1;
        asm volatile("s_waitcnt vmcnt(0)" ::: "memory");
        __builtin_amdgcn_s_barrier();
        __builtin_amdgcn_sched_barrier(0);
        if (c + 1 < nc) {                       // next causal chunk: K+V
            stageKto(c + 1, Ks[buf ^ 1]);
            stageVto(c + 1, Vs[buf ^ 1]);
        } else if (c + 1 < 32) {                // first tail pair into dead buf^1
            stageKto(c + 1, Ks[buf ^ 1]);
            if (c + 2 < 32) stageKto(c + 2, Vs[buf ^ 1]);
        }
        __builtin_amdgcn_sched_barrier(0);

        const int kc = c * 64;
        const bool activ = (kc + kofs <= qmax);         // wave-uniform
        const bool fullc = (kc + kofs + 31 <= qmin);    // wave-uniform

        // ---- QK^T: A = K rows (wave's 32-k half), B = Q regs
        f32x16 s = {};
        __builtin_amdgcn_s_setprio(1);
        for (int m = 0; m < 4; ++m) {
            bf16x8 kf = *(const bf16x8*)&Ks[buf][kofs + l31][(m * 16 + hi * 8) ^ swz];
            s = MFMA32(kf, qB[m], s);
        }
        __builtin_amdgcn_s_setprio(0);

        // ---- exp2 (Q pre-scaled by log2e/8) + denominator (UNmasked, tree sum)
        float e[16];
        for (int r = 0; r < 16; ++r) e[r] = __builtin_exp2f(s[r]);
        {
            float p01 = e[0] + e[1],  p23 = e[2] + e[3];
            float p45 = e[4] + e[5],  p67 = e[6] + e[7];
            float p89 = e[8] + e[9],  pab = e[10] + e[11];
            float pcd = e[12] + e[13], pef = e[14] + e[15];
            float q0 = p01 + p23, q1 = p45 + p67, q2 = p89 + pab, q3 = pcd + pef;
            dsum += (q0 + q1) + (q2 + q3);
        }

        if (activ) {
            if (!fullc) {   // diagonal: tril AFTER softmax
                for (int r = 0; r < 16; ++r) {
                    int kg = kc + kofs + (r & 3) + 8 * (r >> 2) + 4 * hi;
                    if (kg > qrow) e[r] = 0.f;
                }
            }
            // ---- pack P to bf16 + permlane32_swap -> 2 PV A-frags, no LDS
            bf16x8 pf[2];
            {
                unsigned a0 = pk_bf16(e[0], e[1]), a1 = pk_bf16(e[2], e[3]);
                unsigned b0 = pk_bf16(e[4], e[5]), b1 = pk_bf16(e[6], e[7]);
                plane32swap(a0, b0); plane32swap(a1, b1);
                pf[0] = frag_words(a0, a1, b0, b1);
                a0 = pk_bf16(e[8], e[9]);   a1 = pk_bf16(e[10], e[11]);
                b0 = pk_bf16(e[12], e[13]); b1 = pk_bf16(e[14], e[15]);
                plane32swap(a0, b0); plane32swap(a1, b1);
                pf[1] = frag_words(a0, a1, b0, b1);
            }
            // ---- PV: A = P frags, B = V^T tile (col d, row k)
            __builtin_amdgcn_s_setprio(1);
            for (int kt = 0; kt < 2; ++kt) {
                const int col = (kofs + kt * 16 + hi * 8) ^ swz;
                bf16x8 v0 = *(const bf16x8*)&Vs[buf][l31][col];
                bf16x8 v1 = *(const bf16x8*)&Vs[buf][32 + l31][col];
                oacc0 = MFMA32(pf[kt], v0, oacc0);
                oacc1 = MFMA32(pf[kt], v1, oacc1);
            }
            __builtin_amdgcn_s_setprio(0);
        }
    }

    // ---- tail loop: denominator only, two K chunks per round ----
    // pair r occupies {Ks[tb], Vs[tb]} with tb = (nc + r) & 1
    for (int c0 = nc, tr = 0; c0 < 32; c0 += 2, ++tr) {
        const int tb = (nc + tr) & 1;
        asm volatile("s_waitcnt vmcnt(0)" ::: "memory");
        __builtin_amdgcn_s_barrier();
        __builtin_amdgcn_sched_barrier(0);
        if (c0 + 2 < 32) {
            stageKto(c0 + 2, Ks[tb ^ 1]);
            if (c0 + 3 < 32) stageKto(c0 + 3, Vs[tb ^ 1]);
        }
        __builtin_amdgcn_sched_barrier(0);

        const bool two = (c0 + 1 < 32);
        f32x16 sa = {}, sb = {};
        __builtin_amdgcn_s_setprio(1);
        for (int m = 0; m < 4; ++m) {
            bf16x8 kfa = *(const bf16x8*)&Ks[tb][kofs + l31][(m * 16 + hi * 8) ^ swz];
            sa = MFMA32(kfa, qB[m], sa);
        }
        if (two) {
            for (int m = 0; m < 4; ++m) {
                bf16x8 kfb = *(const bf16x8*)&Vs[tb][kofs + l31][(m * 16 + hi * 8) ^ swz];
                sb = MFMA32(kfb, qB[m], sb);
            }
        }
        __builtin_amdgcn_s_setprio(0);

        {
            float ea[16];
            for (int r = 0; r < 16; ++r) ea[r] = __builtin_exp2f(sa[r]);
            float p01 = ea[0] + ea[1],  p23 = ea[2] + ea[3];
            float p45 = ea[4] + ea[5],  p67 = ea[6] + ea[7];
            float p89 = ea[8] + ea[9],  pab = ea[10] + ea[11];
            float pcd = ea[12] + ea[13], pef = ea[14] + ea[15];
            float q0 = p01 + p23, q1 = p45 + p67, q2 = p89 + pab, q3 = pcd + pef;
            dsum += (q0 + q1) + (q2 + q3);
        }
        if (two) {
            float eb[16];
            for (int r = 0; r < 16; ++r) eb[r] = __builtin_exp2f(sb[r]);
            float p01 = eb[0] + eb[1],  p23 = eb[2] + eb[3];
            float p45 = eb[4] + eb[5],  p67 = eb[6] + eb[7];
            float p89 = eb[8] + eb[9],  pab = eb[10] + eb[11];
            float pcd = eb[12] + eb[13], pef = eb[14] + eb[15];
            float q0 = p01 + p23, q1 = p45 + p67, q2 = p89 + pab, q3 = pcd + pef;
            dsum += (q0 + q1) + (q2 + q3);
        }
    }

    // ---- wave-internal k reduce: lane & lane^32 hold complementary k for q=l31
    dsum += __shfl_xor(dsum, 32);

    // ---- cross-pair reduce via LDS overlay (Ks/Vs regions dead after loop)
    __syncthreads();
    float* Ored = (float*)smem;                 // [pair][q 0-31][d 0-63] = 2 x 8KB
    float* dred = (float*)(smem + 16384);       // [wave][q 0-31] = 512 B
    if (l31 == lane) dred[w * 32 + l31] = dsum; // lanes 0-31 only
    if (p == 1) {
        float* Op = Ored + wq * 2048;
        for (int r = 0; r < 16; ++r) {
            const int qoff = (r & 3) + 8 * (r >> 2) + 4 * hi;
            Op[qoff * 64 + l31]      = oacc0[r];
            Op[qoff * 64 + 32 + l31] = oacc1[r];
        }
    }
    __syncthreads();
    if (p == 0) {
        const float dtot = dsum + dred[(w + 1) * 32 + l31];
        const float rall = 1.0f / dtot;          // valid for q=l31 at every lane
        const float* Op = Ored + wq * 2048;
        for (int r = 0; r < 16; ++r) {
            const int qoff = (r & 3) + 8 * (r >> 2) + 4 * hi;
            const float inv = __shfl(rall, qoff);
            const size_t row = (size_t)(t0 + wq * 32 + qoff) * 64;
            Og[row + l31]      = (bf16)((oacc0[r] + Op[qoff * 64 + l31])      * inv);
            Og[row + 32 + l31] = (bf16)((oacc1[r] + Op[qoff * 64 + 32 + l31]) * inv);
        }
    }
}

// ---------------- host ----------------
extern "C" void kernel_launch(void* const* d_in, const int* in_sizes, int n_in,
                              void* d_out, int out_size, void* d_ws, size_t ws_size,
                              hipStream_t stream) {
    const float* query = (const float*)d_in[0];
    const float* key_  = (const float*)d_in[1];
    const float* value = (const float*)d_in[2];
    const float* Wq = (const float*)d_in[3];
    const float* bq = (const float*)d_in[4];
    const float* Wk = (const float*)d_in[5];
    const float* bk = (const float*)d_in[6];
    const float* Wv = (const float*)d_in[7];
    const float* bv = (const float*)d_in[8];
    const float* Wo = (const float*)d_in[9];
    const float* bo = (const float*)d_in[10];
    float* out = (float*)d_out;

    const size_t MN = (size_t)4096 * 768;
    const size_t WW = (size_t)768 * 768;
    bf16* Qp  = (bf16*)d_ws;
    bf16* Kp  = Qp + MN;
    bf16* Vp  = Kp + MN;
    bf16* Obf = Vp + MN;
    bf16* Vtg = Obf + MN;
    bf16* WtQ = Vtg + MN;
    bf16* WtK = WtQ + WW;
    bf16* WtV = WtK + WW;
    bf16* WtO = WtV + WW;
    bf16* Vb  = WtO + WW;    // +1 MN slab
    // bf16 activation inputs: Qb/Kb alias slabs that are only written later
    // (Obf by attn, Vtg by vtrans) — both dead until after gemm<0> consumes them.
    bf16* Qb  = Obf;
    bf16* Kb  = Vtg;

    cvt_qkv<<<dim3(1536, 3), 256, 0, stream>>>(query, key_, value, Qb, Kb, Vb);

    transpose_w<<<dim3(144, 1, 4), 256, 0, stream>>>(
        TArg{Wq, WtQ}, TArg{Wk, WtK}, TArg{Wv, WtV}, TArg{Wo, WtO});

    // fold log2(e)/sqrt(HD) into Q so attention uses native exp2
    gemm_bt_bias<0><<<dim3(6, 32, 3), 256, 0, stream>>>(
        GArg{Qb, WtQ, bq, Qp, 0.18033688f},
        GArg{Kb, WtK, bk, Kp, 1.0f},
        GArg{Vb, WtV, bv, Vp, 1.0f});

    vtrans<<<dim3(32, 24), 256, 0, stream>>>(Vp, Vtg);

    attn_kernel<<<dim3(768), 256, 0, stream>>>(Qp, Kp, Vtg, Obf);

    gemm_bt_bias<1><<<dim3(6, 32, 1), 256, 0, stream>>>(
        GArg{Obf, WtO, bo, out, 1.0f},
        GArg{Obf, WtO, bo, out, 1.0f},
        GArg{Obf, WtO, bo, out, 1.0f});
}

// Round 5
// 111.983 us; speedup vs baseline: 1.4490x; 1.1013x over previous
//
#include <hip/hip_runtime.h>
#include <hip/hip_bf16.h>

// MultiHeadAttentionLegacy: B=2, S=2048, E=768, H=12, HD=64, G=B*H=24
// Inputs fp32, output fp32; internal bf16 MFMA pipeline.
// Legacy reshape = pure flat re-chunk: [4096][768] buffer == 24 slabs [2048][64].
// Softmax denominator over FULL row; tril mask applied AFTER softmax.
// Q projection pre-scaled by log2(e)/sqrt(64) so attention uses exp2 directly.
//
// R1: pre-convert q/k/v fp32->bf16 (gll staging for both GEMM operands).
// R2 (FAILED): deeper attn LDS pipeline -> worse. Not latency-bound.
// R3 (FAILED): direct per-lane L2 reads -> 2x worse. LDS staging is right.
// R4 (FAILED): fewer rounds via tail-pairing -> slightly worse. Round count
//   is not the limiter either.
// R5: LOAD BALANCE. Old swizzle gave a CU three blocks with the SAME bx
//   (same causal workload) -> kernel time = all-bx=31 CUs. New mapping uses
//   three permutations with constant triplet sum (31-t, (15-t)&31, rotl(t,1))
//   so every CU's PV workload is uniform (49/50 units vs 3..96).
//   GEMM: XCD-affine remap (4 row-blocks per XCD, cols fastest) so the A
//   panel is L2-resident per XCD instead of re-fetched 6x from HBM/L3.

typedef __bf16 bf16;
typedef __attribute__((ext_vector_type(4))) __bf16 bf16x4;
typedef __attribute__((ext_vector_type(8))) __bf16 bf16x8;
typedef __attribute__((ext_vector_type(4))) float f32x4;
typedef __attribute__((ext_vector_type(16))) float f32x16;
typedef __attribute__((ext_vector_type(4))) unsigned int uint4v;

#define MFMA16(a,b,c) __builtin_amdgcn_mfma_f32_16x16x32_bf16((a),(b),(c),0,0,0)
#define MFMA32(a,b,c) __builtin_amdgcn_mfma_f32_32x32x16_bf16((a),(b),(c),0,0,0)

typedef const __attribute__((address_space(1))) unsigned int GU32;
typedef __attribute__((address_space(3))) unsigned int LU32;

__device__ __forceinline__ void gll16(const void* gsrc, void* ldst) {
    __builtin_amdgcn_global_load_lds((GU32*)gsrc, (LU32*)ldst, 16, 0, 0);
}

__device__ __forceinline__ unsigned pk_bf16(float lo, float hi) {
    unsigned r;
    asm("v_cvt_pk_bf16_f32 %0, %1, %2" : "=v"(r) : "v"(lo), "v"(hi));
    return r;
}

// v_permlane32_swap_b32: a.hi32lanes <-> b.lo32lanes
__device__ __forceinline__ void plane32swap(unsigned &a, unsigned &b) {
    asm("v_permlane32_swap_b32 %0, %1" : "+v"(a), "+v"(b));
}

__device__ __forceinline__ bf16x8 frag_words(unsigned w0, unsigned w1, unsigned w2, unsigned w3) {
    union { unsigned u[4]; bf16x8 v; } f;
    f.u[0] = w0; f.u[1] = w1; f.u[2] = w2; f.u[3] = w3;
    return f.v;
}

// ------- fp32 -> bf16 streaming convert for q/k/v activations -------
__global__ __launch_bounds__(256) void cvt_qkv(
    const float* __restrict__ q, const float* __restrict__ k, const float* __restrict__ v,
    bf16* __restrict__ Qb, bf16* __restrict__ Kb, bf16* __restrict__ Vb)
{
    const float* src = blockIdx.y == 0 ? q : blockIdx.y == 1 ? k : v;
    bf16* dst = blockIdx.y == 0 ? Qb : blockIdx.y == 1 ? Kb : Vb;
    const size_t base = (size_t)blockIdx.x * 2048 + (size_t)threadIdx.x * 8;
    f32x4 lo = *(const f32x4*)&src[base];
    f32x4 hi = *(const f32x4*)&src[base + 4];
    bf16x8 o;
    for (int j = 0; j < 4; ++j) { o[j] = (bf16)lo[j]; o[4 + j] = (bf16)hi[j]; }
    *(bf16x8*)&dst[base] = o;
}

// ------- weight transpose + cvt: out_bf16[n*768+k] = (bf16)in_f32[k*768+n] -------
struct TArg { const float* in; bf16* out; };

__global__ __launch_bounds__(256) void transpose_w(TArg a0, TArg a1, TArg a2, TArg a3) {
    TArg ta = blockIdx.z == 0 ? a0 : blockIdx.z == 1 ? a1 : blockIdx.z == 2 ? a2 : a3;
    __shared__ bf16 tile[64][72];
    const int bx = blockIdx.x % 12, by = blockIdx.x / 12;
    const int k0 = by * 64, n0 = bx * 64;
    const int tid = threadIdx.x;
    for (int q = 0; q < 2; ++q) {
        int idx = q * 256 + tid;
        int i = idx >> 3, j0 = (idx & 7) * 8;
        const float* src = &ta.in[(size_t)(k0 + i) * 768 + n0 + j0];
        f32x4 lo = *(const f32x4*)&src[0];
        f32x4 hi = *(const f32x4*)&src[4];
        bf16x8 v;
        for (int j = 0; j < 4; ++j) { v[j] = (bf16)lo[j]; v[4 + j] = (bf16)hi[j]; }
        *(bf16x8*)&tile[i][j0] = v;
    }
    __syncthreads();
    for (int q = 0; q < 2; ++q) {
        int idx = q * 256 + tid;
        int n = idx >> 3, j0 = (idx & 7) * 8;
        bf16x8 v;
        for (int jj = 0; jj < 8; ++jj) v[jj] = tile[j0 + jj][n];
        *(bf16x8*)&ta.out[(size_t)(n0 + n) * 768 + k0 + j0] = v;
    }
}

// ------- V slab transpose: Vt[g][d][k] = Vp[g*131072 + k*64 + d] -------
__global__ __launch_bounds__(256) void vtrans(const bf16* __restrict__ Vp, bf16* __restrict__ Vt) {
    __shared__ bf16 tile[64][72];
    const int g = blockIdx.y;
    const int k0 = blockIdx.x * 64;
    const bf16* src = Vp + (size_t)g * 131072;
    bf16* dst = Vt + (size_t)g * 131072;
    const int tid = threadIdx.x;
    for (int q = 0; q < 2; ++q) {
        int idx = q * 256 + tid;
        int r = idx >> 3, c = (idx & 7) * 8;
        *(uint4v*)&tile[r][c] = *(const uint4v*)&src[(size_t)(k0 + r) * 64 + c];
    }
    __syncthreads();
    for (int q = 0; q < 2; ++q) {
        int idx = q * 256 + tid;
        int d = idx >> 3, c = (idx & 7) * 8;
        bf16x8 v;
        for (int j = 0; j < 8; ++j) v[j] = tile[c + j][d];
        *(bf16x8*)&dst[(size_t)d * 2048 + k0 + c] = v;
    }
}

// --- GEMM: C[4096x768] = (A @ Bt^T + bias) * scale.  A is bf16 always.
//     MODE 0: C bf16 (proj);  MODE 1: C fp32 (out)
//     R5: XCD-affine block remap. Each XCD owns 4 row-blocks (A-slice 0.8MB
//     + B 1.2MB fits its 4MB L2); cols vary fastest so the A-tile is reused
//     6x while L2-hot. ---
struct GArg { const bf16* A; const bf16* Bt; const float* bias; void* C; float scale; };

template<int MODE>
__global__ __launch_bounds__(256) void gemm_bt_bias(GArg g0, GArg g1, GArg g2) {
    // flat id -> (xcd, mat, row, col): xcd = flat&7 (HW round-robin),
    // within XCD: mat slow, 4 row-blocks, 6 cols fast. row = xcd*4 + rloc.
    const int flat = blockIdx.x + 6 * blockIdx.y + 192 * blockIdx.z;
    const int xcd = flat & 7;
    const int idx = flat >> 3;          // z=3: 0..71, z=1: 0..23
    const int mat = idx / 24;
    const int rem = idx % 24;
    const int rloc = rem / 6, colb = rem % 6;
    GArg ga = mat == 0 ? g0 : mat == 1 ? g1 : g2;
    const int K = 768, N = 768;
    __shared__ bf16 As[2][128][64];
    __shared__ bf16 Bs[2][128][64];
    const int tid = threadIdx.x;
    const int lane = tid & 63, wave = tid >> 6;
    const int l15 = lane & 15, lg = lane >> 4;
    const int r0 = (xcd * 4 + rloc) * 128, c0 = colb * 128;
    const int wr = (wave >> 1) * 64, wc = (wave & 1) * 64;
    f32x4 acc[4][4] = {};

    const int grow = wave * 8 + (lane >> 3);
    const int gcol = 8 * ((lane & 7) ^ (lane >> 3));

    auto stage = [&](int kt, int buf) {
        for (int i = 0; i < 4; ++i)
            gll16(&ga.A[(size_t)(r0 + i * 32 + grow) * K + kt + gcol], &As[buf][i * 32 + wave * 8][0]);
        for (int i = 0; i < 4; ++i)
            gll16(&ga.Bt[(size_t)(c0 + i * 32 + grow) * K + kt + gcol], &Bs[buf][i * 32 + wave * 8][0]);
    };

    stage(0, 0);
    __syncthreads();

    for (int c = 0; c < 12; ++c) {
        const int buf = c & 1;
        if (c < 11) stage((c + 1) * 64, buf ^ 1);   // fire-and-forget, drained at barrier
        for (int kk = 0; kk < 2; ++kk) {
            bf16x8 af[4], bfr[4];
            for (int i = 0; i < 4; ++i) {
                int row = wr + i * 16 + l15;
                af[i] = *(const bf16x8*)&As[buf][row][(kk * 32 + lg * 8) ^ ((row & 7) * 8)];
            }
            for (int j = 0; j < 4; ++j) {
                int row = wc + j * 16 + l15;
                bfr[j] = *(const bf16x8*)&Bs[buf][row][(kk * 32 + lg * 8) ^ ((row & 7) * 8)];
            }
            __builtin_amdgcn_s_setprio(1);
            for (int i = 0; i < 4; ++i)
                for (int j = 0; j < 4; ++j)
                    acc[i][j] = MFMA16(af[i], bfr[j], acc[i][j]);
            __builtin_amdgcn_s_setprio(0);
        }
        __syncthreads();
    }
    for (int j = 0; j < 4; ++j) {
        int col = c0 + wc + j * 16 + l15;
        float bv = ga.bias[col];
        for (int i = 0; i < 4; ++i) {
            int row = r0 + wr + i * 16 + lg * 4;
            for (int r = 0; r < 4; ++r) {
                float val = (acc[i][j][r] + bv) * ga.scale;
                if constexpr (MODE == 0)
                    ((bf16*)ga.C)[(size_t)(row + r) * N + col] = (bf16)val;
                else
                    ((float*)ga.C)[(size_t)(row + r) * N + col] = val;
            }
        }
    }
}

// ------- attention v9: v5 structure + balanced bx triplets -------
// Block = 4 waves over 64 q-rows. Wave (wq=w>>1, p=w&1): q rows t0+wq*32..+31,
// k-half p of each 64-chunk. Swapped QK: S-regs q=lane&31, k=(r&3)+8*(r>>2)+4*hi.
// bid mapping: xcd = bid&7 keeps K/V L2-local (3 groups/XCD). Within an XCD,
// slots s=0,1,2 (co-resident on a CU at stride 256) get bx from three
// permutations with CONSTANT triplet sum: 31-t, (15-t)&31, rotl5(t,1)
// -> every CU's causal-PV workload is 49/50 units (was 3..96).
__global__ __launch_bounds__(256) void attn_kernel(
    const bf16* __restrict__ Qp, const bf16* __restrict__ Kp,
    const bf16* __restrict__ Vtg, bf16* __restrict__ Ob)
{
    const int bid = blockIdx.x;
    const int xcd = bid & 7;
    const int idx = bid >> 3;            // 0..95
    const int t = idx & 31, s = idx >> 5;
    const int bx = (s == 0) ? (31 - t)
                 : (s == 1) ? ((15 - t) & 31)
                 : (((t << 1) & 31) | (t >> 4));
    const int g = xcd * 3 + s;
    const int t0 = bx * 64;
    const int tid = threadIdx.x, lane = tid & 63, w = tid >> 6;
    const int wq = w >> 1, p = w & 1;
    const int l31 = lane & 31, hi = lane >> 5;

    __shared__ __align__(16) char smem[32768];
    bf16 (*Ks)[64][64] = (bf16(*)[64][64])smem;             // [2][k][d], d-swizzled
    bf16 (*Vs)[64][64] = (bf16(*)[64][64])(smem + 16384);   // [2][d][k], k-swizzled

    const bf16* Qg = Qp + (size_t)g * 131072;
    const bf16* Kg = Kp + (size_t)g * 131072;
    const bf16* Vg = Vtg + (size_t)g * 131072;   // [64][2048]
    bf16* Og = Ob + (size_t)g * 131072;

    // Q B-frags in registers: col=q=l31, k-dim d = m*16 + hi*8 + j
    const int qrow = t0 + wq * 32 + l31;
    bf16x8 qB[4];
    for (int m = 0; m < 4; ++m)
        qB[m] = *(const bf16x8*)&Qg[(size_t)qrow * 64 + m * 16 + hi * 8];

    // staging: wave stages 16 rows (2 gll of 8 rows), pre-swizzled source col
    const int srow = w * 16 + (lane >> 3);
    const int scol = 8 * ((lane & 7) ^ (lane >> 3));
    auto stageK = [&](int ch, int b2) {
        const bf16* src = &Kg[(size_t)(ch * 64 + srow) * 64 + scol];
        gll16(src, &Ks[b2][w * 16][0]);
        gll16(src + 8 * 64, &Ks[b2][w * 16 + 8][0]);
    };
    auto stageV = [&](int ch, int b2) {
        const bf16* src = &Vg[(size_t)srow * 2048 + ch * 64 + scol];
        gll16(src, &Vs[b2][w * 16][0]);
        gll16(src + 8 * 2048, &Vs[b2][w * 16 + 8][0]);
    };

    stageK(0, 0);
    stageV(0, 0);

    f32x16 oacc0 = {}, oacc1 = {};
    float dsum = 0.f;
    const int qmin = t0 + wq * 32, qmax = qmin + 31;   // wave's q range
    const int kofs = p * 32;                            // wave's k-half offset
    const int swz = (l31 & 7) * 8;

    for (int c = 0; c < 32; ++c) {
        const int b = c & 1;
        asm volatile("s_waitcnt vmcnt(0)" ::: "memory");
        __builtin_amdgcn_s_barrier();
        __builtin_amdgcn_sched_barrier(0);
        if (c < 31) {
            stageK(c + 1, b ^ 1);
            if (c + 1 <= bx) stageV(c + 1, b ^ 1);
        }
        __builtin_amdgcn_sched_barrier(0);

        const int kc = c * 64;
        const bool activ = (kc + kofs <= qmax);         // wave-uniform
        const bool fullc = (kc + kofs + 31 <= qmin);    // wave-uniform

        // ---- QK^T: A = K rows (wave's 32-k half), B = Q regs
        f32x16 s = {};
        __builtin_amdgcn_s_setprio(1);
        for (int m = 0; m < 4; ++m) {
            bf16x8 kf = *(const bf16x8*)&Ks[b][kofs + l31][(m * 16 + hi * 8) ^ swz];
            s = MFMA32(kf, qB[m], s);
        }
        __builtin_amdgcn_s_setprio(0);

        // ---- exp2 (Q pre-scaled by log2e/8) + denominator (UNmasked, tree sum)
        float e[16];
        for (int r = 0; r < 16; ++r) e[r] = __builtin_exp2f(s[r]);
        {
            float p01 = e[0] + e[1],  p23 = e[2] + e[3];
            float p45 = e[4] + e[5],  p67 = e[6] + e[7];
            float p89 = e[8] + e[9],  pab = e[10] + e[11];
            float pcd = e[12] + e[13], pef = e[14] + e[15];
            float q0 = p01 + p23, q1 = p45 + p67, q2 = p89 + pab, q3 = pcd + pef;
            dsum += (q0 + q1) + (q2 + q3);
        }

        if (activ) {
            if (!fullc) {   // diagonal: tril AFTER softmax
                for (int r = 0; r < 16; ++r) {
                    int kg = kc + kofs + (r & 3) + 8 * (r >> 2) + 4 * hi;
                    if (kg > qrow) e[r] = 0.f;
                }
            }
            // ---- pack P to bf16 + permlane32_swap -> 2 PV A-frags, no LDS
            bf16x8 pf[2];
            {
                unsigned a0 = pk_bf16(e[0], e[1]), a1 = pk_bf16(e[2], e[3]);
                unsigned b0 = pk_bf16(e[4], e[5]), b1 = pk_bf16(e[6], e[7]);
                plane32swap(a0, b0); plane32swap(a1, b1);
                pf[0] = frag_words(a0, a1, b0, b1);
                a0 = pk_bf16(e[8], e[9]);   a1 = pk_bf16(e[10], e[11]);
                b0 = pk_bf16(e[12], e[13]); b1 = pk_bf16(e[14], e[15]);
                plane32swap(a0, b0); plane32swap(a1, b1);
                pf[1] = frag_words(a0, a1, b0, b1);
            }
            // ---- PV: A = P frags, B = V^T tile (col d, row k)
            __builtin_amdgcn_s_setprio(1);
            for (int kt = 0; kt < 2; ++kt) {
                const int col = (kofs + kt * 16 + hi * 8) ^ swz;
                bf16x8 v0 = *(const bf16x8*)&Vs[b][l31][col];
                bf16x8 v1 = *(const bf16x8*)&Vs[b][32 + l31][col];
                oacc0 = MFMA32(pf[kt], v0, oacc0);
                oacc1 = MFMA32(pf[kt], v1, oacc1);
            }
            __builtin_amdgcn_s_setprio(0);
        }
    }

    // ---- wave-internal k reduce: lane & lane^32 hold complementary k for q=l31
    dsum += __shfl_xor(dsum, 32);

    // ---- cross-pair reduce via LDS overlay (Ks/Vs regions dead after loop)
    __syncthreads();
    float* Ored = (float*)smem;                 // [pair][q 0-31][d 0-63] = 2 x 8KB
    float* dred = (float*)(smem + 16384);       // [wave][q 0-31] = 512 B
    if (l31 == lane) dred[w * 32 + l31] = dsum; // lanes 0-31 only
    if (p == 1) {
        float* Op = Ored + wq * 2048;
        for (int r = 0; r < 16; ++r) {
            const int qoff = (r & 3) + 8 * (r >> 2) + 4 * hi;
            Op[qoff * 64 + l31]      = oacc0[r];
            Op[qoff * 64 + 32 + l31] = oacc1[r];
        }
    }
    __syncthreads();
    if (p == 0) {
        const float dtot = dsum + dred[(w + 1) * 32 + l31];
        const float rall = 1.0f / dtot;          // valid for q=l31 at every lane
        const float* Op = Ored + wq * 2048;
        for (int r = 0; r < 16; ++r) {
            const int qoff = (r & 3) + 8 * (r >> 2) + 4 * hi;
            const float inv = __shfl(rall, qoff);
            const size_t row = (size_t)(t0 + wq * 32 + qoff) * 64;
            Og[row + l31]      = (bf16)((oacc0[r] + Op[qoff * 64 + l31])      * inv);
            Og[row + 32 + l31] = (bf16)((oacc1[r] + Op[qoff * 64 + 32 + l31]) * inv);
        }
    }
}

// ---------------- host ----------------
extern "C" void kernel_launch(void* const* d_in, const int* in_sizes, int n_in,
                              void* d_out, int out_size, void* d_ws, size_t ws_size,
                              hipStream_t stream) {
    const float* query = (const float*)d_in[0];
    const float* key_  = (const float*)d_in[1];
    const float* value = (const float*)d_in[2];
    const float* Wq = (const float*)d_in[3];
    const float* bq = (const float*)d_in[4];
    const float* Wk = (const float*)d_in[5];
    const float* bk = (const float*)d_in[6];
    const float* Wv = (const float*)d_in[7];
    const float* bv = (const float*)d_in[8];
    const float* Wo = (const float*)d_in[9];
    const float* bo = (const float*)d_in[10];
    float* out = (float*)d_out;

    const size_t MN = (size_t)4096 * 768;
    const size_t WW = (size_t)768 * 768;
    bf16* Qp  = (bf16*)d_ws;
    bf16* Kp  = Qp + MN;
    bf16* Vp  = Kp + MN;
    bf16* Obf = Vp + MN;
    bf16* Vtg = Obf + MN;
    bf16* WtQ = Vtg + MN;
    bf16* WtK = WtQ + WW;
    bf16* WtV = WtK + WW;
    bf16* WtO = WtV + WW;
    bf16* Vb  = WtO + WW;    // +1 MN slab
    // bf16 activation inputs: Qb/Kb alias slabs that are only written later
    // (Obf by attn, Vtg by vtrans) — both dead until after gemm<0> consumes them.
    bf16* Qb  = Obf;
    bf16* Kb  = Vtg;

    cvt_qkv<<<dim3(1536, 3), 256, 0, stream>>>(query, key_, value, Qb, Kb, Vb);

    transpose_w<<<dim3(144, 1, 4), 256, 0, stream>>>(
        TArg{Wq, WtQ}, TArg{Wk, WtK}, TArg{Wv, WtV}, TArg{Wo, WtO});

    // fold log2(e)/sqrt(HD) into Q so attention uses native exp2
    gemm_bt_bias<0><<<dim3(6, 32, 3), 256, 0, stream>>>(
        GArg{Qb, WtQ, bq, Qp, 0.18033688f},
        GArg{Kb, WtK, bk, Kp, 1.0f},
        GArg{Vb, WtV, bv, Vp, 1.0f});

    vtrans<<<dim3(32, 24), 256, 0, stream>>>(Vp, Vtg);

    attn_kernel<<<dim3(768), 256, 0, stream>>>(Qp, Kp, Vtg, Obf);

    gemm_bt_bias<1><<<dim3(6, 32, 1), 256, 0, stream>>>(
        GArg{Obf, WtO, bo, out, 1.0f},
        GArg{Obf, WtO, bo, out, 1.0f},
        GArg{Obf, WtO, bo, out, 1.0f});
}

// Round 6
// 109.061 us; speedup vs baseline: 1.4879x; 1.0268x over previous
//
#include <hip/hip_runtime.h>
#include <hip/hip_bf16.h>

// MultiHeadAttentionLegacy: B=2, S=2048, E=768, H=12, HD=64, G=B*H=24
// Inputs fp32, output fp32; internal bf16 MFMA pipeline.
// Legacy reshape = pure flat re-chunk: [4096][768] buffer == 24 slabs [2048][64].
// Softmax denominator over FULL row; tril mask applied AFTER softmax.
// Q projection pre-scaled by log2(e)/sqrt(64) so attention uses exp2 directly.
//
// R1: pre-convert q/k/v fp32->bf16 (gll staging for both GEMM operands).
// R2 (FAILED): deeper attn LDS pipeline -> worse. Not latency-bound.
// R3 (FAILED): direct per-lane L2 reads -> 2x worse. LDS staging is right.
// R4 (FAILED): fewer rounds via tail-pairing -> slightly worse.
// R5 (WIN): constant-sum bx triplets balance per-CU PV load (attn -6us);
//   XCD-affine GEMM remap (A panel L2-resident).
// R6: attn was compiled at VGPR=64 (bare launch_bounds targets 8 waves/SIMD)
//   while the grid only gives 3 blocks/CU -> compiler remat'd loop-invariant
//   LDS addresses every round, inflating VALU (58% busy). Declare
//   __launch_bounds__(256,3) (<=168 VGPR) and hoist all LDS read offsets
//   into registers; buffer toggle is a +8192-element XOR.

typedef __bf16 bf16;
typedef __attribute__((ext_vector_type(4))) __bf16 bf16x4;
typedef __attribute__((ext_vector_type(8))) __bf16 bf16x8;
typedef __attribute__((ext_vector_type(4))) float f32x4;
typedef __attribute__((ext_vector_type(16))) float f32x16;
typedef __attribute__((ext_vector_type(4))) unsigned int uint4v;

#define MFMA16(a,b,c) __builtin_amdgcn_mfma_f32_16x16x32_bf16((a),(b),(c),0,0,0)
#define MFMA32(a,b,c) __builtin_amdgcn_mfma_f32_32x32x16_bf16((a),(b),(c),0,0,0)

typedef const __attribute__((address_space(1))) unsigned int GU32;
typedef __attribute__((address_space(3))) unsigned int LU32;

__device__ __forceinline__ void gll16(const void* gsrc, void* ldst) {
    __builtin_amdgcn_global_load_lds((GU32*)gsrc, (LU32*)ldst, 16, 0, 0);
}

__device__ __forceinline__ unsigned pk_bf16(float lo, float hi) {
    unsigned r;
    asm("v_cvt_pk_bf16_f32 %0, %1, %2" : "=v"(r) : "v"(lo), "v"(hi));
    return r;
}

// v_permlane32_swap_b32: a.hi32lanes <-> b.lo32lanes
__device__ __forceinline__ void plane32swap(unsigned &a, unsigned &b) {
    asm("v_permlane32_swap_b32 %0, %1" : "+v"(a), "+v"(b));
}

__device__ __forceinline__ bf16x8 frag_words(unsigned w0, unsigned w1, unsigned w2, unsigned w3) {
    union { unsigned u[4]; bf16x8 v; } f;
    f.u[0] = w0; f.u[1] = w1; f.u[2] = w2; f.u[3] = w3;
    return f.v;
}

// ------- fp32 -> bf16 streaming convert for q/k/v activations -------
__global__ __launch_bounds__(256) void cvt_qkv(
    const float* __restrict__ q, const float* __restrict__ k, const float* __restrict__ v,
    bf16* __restrict__ Qb, bf16* __restrict__ Kb, bf16* __restrict__ Vb)
{
    const float* src = blockIdx.y == 0 ? q : blockIdx.y == 1 ? k : v;
    bf16* dst = blockIdx.y == 0 ? Qb : blockIdx.y == 1 ? Kb : Vb;
    const size_t base = (size_t)blockIdx.x * 2048 + (size_t)threadIdx.x * 8;
    f32x4 lo = *(const f32x4*)&src[base];
    f32x4 hi = *(const f32x4*)&src[base + 4];
    bf16x8 o;
    for (int j = 0; j < 4; ++j) { o[j] = (bf16)lo[j]; o[4 + j] = (bf16)hi[j]; }
    *(bf16x8*)&dst[base] = o;
}

// ------- weight transpose + cvt: out_bf16[n*768+k] = (bf16)in_f32[k*768+n] -------
struct TArg { const float* in; bf16* out; };

__global__ __launch_bounds__(256) void transpose_w(TArg a0, TArg a1, TArg a2, TArg a3) {
    TArg ta = blockIdx.z == 0 ? a0 : blockIdx.z == 1 ? a1 : blockIdx.z == 2 ? a2 : a3;
    __shared__ bf16 tile[64][72];
    const int bx = blockIdx.x % 12, by = blockIdx.x / 12;
    const int k0 = by * 64, n0 = bx * 64;
    const int tid = threadIdx.x;
    for (int q = 0; q < 2; ++q) {
        int idx = q * 256 + tid;
        int i = idx >> 3, j0 = (idx & 7) * 8;
        const float* src = &ta.in[(size_t)(k0 + i) * 768 + n0 + j0];
        f32x4 lo = *(const f32x4*)&src[0];
        f32x4 hi = *(const f32x4*)&src[4];
        bf16x8 v;
        for (int j = 0; j < 4; ++j) { v[j] = (bf16)lo[j]; v[4 + j] = (bf16)hi[j]; }
        *(bf16x8*)&tile[i][j0] = v;
    }
    __syncthreads();
    for (int q = 0; q < 2; ++q) {
        int idx = q * 256 + tid;
        int n = idx >> 3, j0 = (idx & 7) * 8;
        bf16x8 v;
        for (int jj = 0; jj < 8; ++jj) v[jj] = tile[j0 + jj][n];
        *(bf16x8*)&ta.out[(size_t)(n0 + n) * 768 + k0 + j0] = v;
    }
}

// ------- V slab transpose: Vt[g][d][k] = Vp[g*131072 + k*64 + d] -------
__global__ __launch_bounds__(256) void vtrans(const bf16* __restrict__ Vp, bf16* __restrict__ Vt) {
    __shared__ bf16 tile[64][72];
    const int g = blockIdx.y;
    const int k0 = blockIdx.x * 64;
    const bf16* src = Vp + (size_t)g * 131072;
    bf16* dst = Vt + (size_t)g * 131072;
    const int tid = threadIdx.x;
    for (int q = 0; q < 2; ++q) {
        int idx = q * 256 + tid;
        int r = idx >> 3, c = (idx & 7) * 8;
        *(uint4v*)&tile[r][c] = *(const uint4v*)&src[(size_t)(k0 + r) * 64 + c];
    }
    __syncthreads();
    for (int q = 0; q < 2; ++q) {
        int idx = q * 256 + tid;
        int d = idx >> 3, c = (idx & 7) * 8;
        bf16x8 v;
        for (int j = 0; j < 8; ++j) v[j] = tile[c + j][d];
        *(bf16x8*)&dst[(size_t)d * 2048 + k0 + c] = v;
    }
}

// --- GEMM: C[4096x768] = (A @ Bt^T + bias) * scale.  A is bf16 always.
//     MODE 0: C bf16 (proj);  MODE 1: C fp32 (out)
//     R5: XCD-affine block remap. Each XCD owns 4 row-blocks (A-slice 0.8MB
//     + B 1.2MB fits its 4MB L2); cols vary fastest so the A-tile is reused
//     6x while L2-hot. ---
struct GArg { const bf16* A; const bf16* Bt; const float* bias; void* C; float scale; };

template<int MODE>
__global__ __launch_bounds__(256) void gemm_bt_bias(GArg g0, GArg g1, GArg g2) {
    // flat id -> (xcd, mat, row, col): xcd = flat&7 (HW round-robin),
    // within XCD: mat slow, 4 row-blocks, 6 cols fast. row = xcd*4 + rloc.
    const int flat = blockIdx.x + 6 * blockIdx.y + 192 * blockIdx.z;
    const int xcd = flat & 7;
    const int idx = flat >> 3;          // z=3: 0..71, z=1: 0..23
    const int mat = idx / 24;
    const int rem = idx % 24;
    const int rloc = rem / 6, colb = rem % 6;
    GArg ga = mat == 0 ? g0 : mat == 1 ? g1 : g2;
    const int K = 768, N = 768;
    __shared__ bf16 As[2][128][64];
    __shared__ bf16 Bs[2][128][64];
    const int tid = threadIdx.x;
    const int lane = tid & 63, wave = tid >> 6;
    const int l15 = lane & 15, lg = lane >> 4;
    const int r0 = (xcd * 4 + rloc) * 128, c0 = colb * 128;
    const int wr = (wave >> 1) * 64, wc = (wave & 1) * 64;
    f32x4 acc[4][4] = {};

    const int grow = wave * 8 + (lane >> 3);
    const int gcol = 8 * ((lane & 7) ^ (lane >> 3));

    auto stage = [&](int kt, int buf) {
        for (int i = 0; i < 4; ++i)
            gll16(&ga.A[(size_t)(r0 + i * 32 + grow) * K + kt + gcol], &As[buf][i * 32 + wave * 8][0]);
        for (int i = 0; i < 4; ++i)
            gll16(&ga.Bt[(size_t)(c0 + i * 32 + grow) * K + kt + gcol], &Bs[buf][i * 32 + wave * 8][0]);
    };

    stage(0, 0);
    __syncthreads();

    for (int c = 0; c < 12; ++c) {
        const int buf = c & 1;
        if (c < 11) stage((c + 1) * 64, buf ^ 1);   // fire-and-forget, drained at barrier
        for (int kk = 0; kk < 2; ++kk) {
            bf16x8 af[4], bfr[4];
            for (int i = 0; i < 4; ++i) {
                int row = wr + i * 16 + l15;
                af[i] = *(const bf16x8*)&As[buf][row][(kk * 32 + lg * 8) ^ ((row & 7) * 8)];
            }
            for (int j = 0; j < 4; ++j) {
                int row = wc + j * 16 + l15;
                bfr[j] = *(const bf16x8*)&Bs[buf][row][(kk * 32 + lg * 8) ^ ((row & 7) * 8)];
            }
            __builtin_amdgcn_s_setprio(1);
            for (int i = 0; i < 4; ++i)
                for (int j = 0; j < 4; ++j)
                    acc[i][j] = MFMA16(af[i], bfr[j], acc[i][j]);
            __builtin_amdgcn_s_setprio(0);
        }
        __syncthreads();
    }
    for (int j = 0; j < 4; ++j) {
        int col = c0 + wc + j * 16 + l15;
        float bv = ga.bias[col];
        for (int i = 0; i < 4; ++i) {
            int row = r0 + wr + i * 16 + lg * 4;
            for (int r = 0; r < 4; ++r) {
                float val = (acc[i][j][r] + bv) * ga.scale;
                if constexpr (MODE == 0)
                    ((bf16*)ga.C)[(size_t)(row + r) * N + col] = (bf16)val;
                else
                    ((float*)ga.C)[(size_t)(row + r) * N + col] = val;
            }
        }
    }
}

// ------- attention v10: v9 + VGPR headroom + hoisted LDS offsets -------
// Block = 4 waves over 64 q-rows. Wave (wq=w>>1, p=w&1): q rows t0+wq*32..+31,
// k-half p of each 64-chunk. Swapped QK: S-regs q=lane&31, k=(r&3)+8*(r>>2)+4*hi.
// bid mapping: xcd = bid&7 keeps K/V L2-local; within an XCD the three slots
// use constant-sum bx permutations (31-t, (15-t)&31, rotl5(t,1)).
// launch_bounds(256,3): grid gives exactly 3 blocks/CU, so allow <=168 VGPR
// instead of the default 64 -> no loop-invariant address remat.
__global__ __launch_bounds__(256, 3) void attn_kernel(
    const bf16* __restrict__ Qp, const bf16* __restrict__ Kp,
    const bf16* __restrict__ Vtg, bf16* __restrict__ Ob)
{
    const int bid = blockIdx.x;
    const int xcd = bid & 7;
    const int idx = bid >> 3;            // 0..95
    const int t = idx & 31, s = idx >> 5;
    const int bx = (s == 0) ? (31 - t)
                 : (s == 1) ? ((15 - t) & 31)
                 : (((t << 1) & 31) | (t >> 4));
    const int g = xcd * 3 + s;
    const int t0 = bx * 64;
    const int tid = threadIdx.x, lane = tid & 63, w = tid >> 6;
    const int wq = w >> 1, p = w & 1;
    const int l31 = lane & 31, hi = lane >> 5;

    __shared__ __align__(16) char smem[32768];
    // Ks buffer b at smem + b*8192 (elements: b*4096): [64][64] bf16, d-swizzled
    // Vs buffer b at smem + 16384 + b*8192: [64][64] bf16 (V^T: [d][k]), k-swizzled
    bf16* KsE = (bf16*)smem;
    bf16* VsE = (bf16*)(smem + 16384);

    const bf16* Qg = Qp + (size_t)g * 131072;
    const bf16* Kg = Kp + (size_t)g * 131072;
    const bf16* Vg = Vtg + (size_t)g * 131072;   // [64][2048]
    bf16* Og = Ob + (size_t)g * 131072;

    // Q B-frags in registers: col=q=l31, k-dim d = m*16 + hi*8 + j
    const int qrow = t0 + wq * 32 + l31;
    bf16x8 qB[4];
    for (int m = 0; m < 4; ++m)
        qB[m] = *(const bf16x8*)&Qg[(size_t)qrow * 64 + m * 16 + hi * 8];

    // staging: wave stages 16 rows (2 gll of 8 rows), pre-swizzled source col
    const int srow = w * 16 + (lane >> 3);
    const int scol = 8 * ((lane & 7) ^ (lane >> 3));
    auto stageK = [&](int ch, int b2) {
        const bf16* src = &Kg[(size_t)(ch * 64 + srow) * 64 + scol];
        bf16* dst = KsE + b2 * 4096 + w * 16 * 64;
        gll16(src, dst);
        gll16(src + 8 * 64, dst + 8 * 64);
    };
    auto stageV = [&](int ch, int b2) {
        const bf16* src = &Vg[(size_t)srow * 2048 + ch * 64 + scol];
        bf16* dst = VsE + b2 * 4096 + w * 16 * 64;
        gll16(src, dst);
        gll16(src + 8 * 2048, dst + 8 * 64);
    };

    stageK(0, 0);
    stageV(0, 0);

    f32x16 oacc0 = {}, oacc1 = {};
    float dsum = 0.f;
    const int qmax = t0 + wq * 32 + 31;                 // wave's q range top
    const int qmin = t0 + wq * 32;
    const int kofs = p * 32;                            // wave's k-half offset
    const int swz = (l31 & 7) * 8;

    // hoisted per-lane LDS element offsets (loop-invariant; buffer = +4096)
    int koff[4], voff0[2], voff1[2];
    for (int m = 0; m < 4; ++m)
        koff[m] = (kofs + l31) * 64 + ((m * 16 + hi * 8) ^ swz);
    for (int kt = 0; kt < 2; ++kt) {
        const int col = (kofs + kt * 16 + hi * 8) ^ swz;
        voff0[kt] = l31 * 64 + col;
        voff1[kt] = (32 + l31) * 64 + col;
    }

    for (int c = 0; c < 32; ++c) {
        const int boff = (c & 1) * 4096;
        asm volatile("s_waitcnt vmcnt(0)" ::: "memory");
        __builtin_amdgcn_s_barrier();
        __builtin_amdgcn_sched_barrier(0);
        if (c < 31) {
            stageK(c + 1, (c & 1) ^ 1);
            if (c + 1 <= bx) stageV(c + 1, (c & 1) ^ 1);
        }
        __builtin_amdgcn_sched_barrier(0);

        const int kc = c * 64;
        const bool activ = (kc + kofs <= qmax);         // wave-uniform
        const bool fullc = (kc + kofs + 31 <= qmin);    // wave-uniform

        // ---- QK^T: A = K rows (wave's 32-k half), B = Q regs
        f32x16 s = {};
        __builtin_amdgcn_s_setprio(1);
        for (int m = 0; m < 4; ++m) {
            bf16x8 kf = *(const bf16x8*)&KsE[boff + koff[m]];
            s = MFMA32(kf, qB[m], s);
        }
        __builtin_amdgcn_s_setprio(0);

        // ---- exp2 (Q pre-scaled by log2e/8) + denominator (UNmasked, tree sum)
        float e[16];
        for (int r = 0; r < 16; ++r) e[r] = __builtin_exp2f(s[r]);
        {
            float p01 = e[0] + e[1],  p23 = e[2] + e[3];
            float p45 = e[4] + e[5],  p67 = e[6] + e[7];
            float p89 = e[8] + e[9],  pab = e[10] + e[11];
            float pcd = e[12] + e[13], pef = e[14] + e[15];
            float q0 = p01 + p23, q1 = p45 + p67, q2 = p89 + pab, q3 = pcd + pef;
            dsum += (q0 + q1) + (q2 + q3);
        }

        if (activ) {
            if (!fullc) {   // diagonal: tril AFTER softmax
                for (int r = 0; r < 16; ++r) {
                    int kg = kc + kofs + (r & 3) + 8 * (r >> 2) + 4 * hi;
                    if (kg > qrow) e[r] = 0.f;
                }
            }
            // ---- pack P to bf16 + permlane32_swap -> 2 PV A-frags, no LDS
            bf16x8 pf[2];
            {
                unsigned a0 = pk_bf16(e[0], e[1]), a1 = pk_bf16(e[2], e[3]);
                unsigned b0 = pk_bf16(e[4], e[5]), b1 = pk_bf16(e[6], e[7]);
                plane32swap(a0, b0); plane32swap(a1, b1);
                pf[0] = frag_words(a0, a1, b0, b1);
                a0 = pk_bf16(e[8], e[9]);   a1 = pk_bf16(e[10], e[11]);
                b0 = pk_bf16(e[12], e[13]); b1 = pk_bf16(e[14], e[15]);
                plane32swap(a0, b0); plane32swap(a1, b1);
                pf[1] = frag_words(a0, a1, b0, b1);
            }
            // ---- PV: A = P frags, B = V^T tile (col d, row k)
            __builtin_amdgcn_s_setprio(1);
            for (int kt = 0; kt < 2; ++kt) {
                bf16x8 v0 = *(const bf16x8*)&VsE[boff + voff0[kt]];
                bf16x8 v1 = *(const bf16x8*)&VsE[boff + voff1[kt]];
                oacc0 = MFMA32(pf[kt], v0, oacc0);
                oacc1 = MFMA32(pf[kt], v1, oacc1);
            }
            __builtin_amdgcn_s_setprio(0);
        }
    }

    // ---- wave-internal k reduce: lane & lane^32 hold complementary k for q=l31
    dsum += __shfl_xor(dsum, 32);

    // ---- cross-pair reduce via LDS overlay (Ks/Vs regions dead after loop)
    __syncthreads();
    float* Ored = (float*)smem;                 // [pair][q 0-31][d 0-63] = 2 x 8KB
    float* dred = (float*)(smem + 16384);       // [wave][q 0-31] = 512 B
    if (l31 == lane) dred[w * 32 + l31] = dsum; // lanes 0-31 only
    if (p == 1) {
        float* Op = Ored + wq * 2048;
        for (int r = 0; r < 16; ++r) {
            const int qoff = (r & 3) + 8 * (r >> 2) + 4 * hi;
            Op[qoff * 64 + l31]      = oacc0[r];
            Op[qoff * 64 + 32 + l31] = oacc1[r];
        }
    }
    __syncthreads();
    if (p == 0) {
        const float dtot = dsum + dred[(w + 1) * 32 + l31];
        const float rall = 1.0f / dtot;          // valid for q=l31 at every lane
        const float* Op = Ored + wq * 2048;
        for (int r = 0; r < 16; ++r) {
            const int qoff = (r & 3) + 8 * (r >> 2) + 4 * hi;
            const float inv = __shfl(rall, qoff);
            const size_t row = (size_t)(t0 + wq * 32 + qoff) * 64;
            Og[row + l31]      = (bf16)((oacc0[r] + Op[qoff * 64 + l31])      * inv);
            Og[row + 32 + l31] = (bf16)((oacc1[r] + Op[qoff * 64 + 32 + l31]) * inv);
        }
    }
}

// ---------------- host ----------------
extern "C" void kernel_launch(void* const* d_in, const int* in_sizes, int n_in,
                              void* d_out, int out_size, void* d_ws, size_t ws_size,
                              hipStream_t stream) {
    const float* query = (const float*)d_in[0];
    const float* key_  = (const float*)d_in[1];
    const float* value = (const float*)d_in[2];
    const float* Wq = (const float*)d_in[3];
    const float* bq = (const float*)d_in[4];
    const float* Wk = (const float*)d_in[5];
    const float* bk = (const float*)d_in[6];
    const float* Wv = (const float*)d_in[7];
    const float* bv = (const float*)d_in[8];
    const float* Wo = (const float*)d_in[9];
    const float* bo = (const float*)d_in[10];
    float* out = (float*)d_out;

    const size_t MN = (size_t)4096 * 768;
    const size_t WW = (size_t)768 * 768;
    bf16* Qp  = (bf16*)d_ws;
    bf16* Kp  = Qp + MN;
    bf16* Vp  = Kp + MN;
    bf16* Obf = Vp + MN;
    bf16* Vtg = Obf + MN;
    bf16* WtQ = Vtg + MN;
    bf16* WtK = WtQ + WW;
    bf16* WtV = WtK + WW;
    bf16* WtO = WtV + WW;
    bf16* Vb  = WtO + WW;    // +1 MN slab
    // bf16 activation inputs: Qb/Kb alias slabs that are only written later
    // (Obf by attn, Vtg by vtrans) — both dead until after gemm<0> consumes them.
    bf16* Qb  = Obf;
    bf16* Kb  = Vtg;

    cvt_qkv<<<dim3(1536, 3), 256, 0, stream>>>(query, key_, value, Qb, Kb, Vb);

    transpose_w<<<dim3(144, 1, 4), 256, 0, stream>>>(
        TArg{Wq, WtQ}, TArg{Wk, WtK}, TArg{Wv, WtV}, TArg{Wo, WtO});

    // fold log2(e)/sqrt(HD) into Q so attention uses native exp2
    gemm_bt_bias<0><<<dim3(6, 32, 3), 256, 0, stream>>>(
        GArg{Qb, WtQ, bq, Qp, 0.18033688f},
        GArg{Kb, WtK, bk, Kp, 1.0f},
        GArg{Vb, WtV, bv, Vp, 1.0f});

    vtrans<<<dim3(32, 24), 256, 0, stream>>>(Vp, Vtg);

    attn_kernel<<<dim3(768), 256, 0, stream>>>(Qp, Kp, Vtg, Obf);

    gemm_bt_bias<1><<<dim3(6, 32, 1), 256, 0, stream>>>(
        GArg{Obf, WtO, bo, out, 1.0f},
        GArg{Obf, WtO, bo, out, 1.0f},
        GArg{Obf, WtO, bo, out, 1.0f});
}

// Round 7
// 107.216 us; speedup vs baseline: 1.5135x; 1.0172x over previous
//
#include <hip/hip_runtime.h>
#include <hip/hip_bf16.h>

// MultiHeadAttentionLegacy: B=2, S=2048, E=768, H=12, HD=64, G=B*H=24
// Inputs fp32, output fp32; internal bf16 MFMA pipeline.
// Legacy reshape = pure flat re-chunk: [4096][768] buffer == 24 slabs [2048][64].
// Softmax denominator over FULL row; tril mask applied AFTER softmax.
// Q projection pre-scaled by log2(e)/sqrt(64) so attention uses exp2 directly.
//
// R1: pre-convert q/k/v fp32->bf16 (gll staging for both GEMM operands).
// R2 (FAILED): deeper attn LDS pipeline -> worse. Not latency-bound.
// R3 (FAILED): direct per-lane L2 reads -> 2x worse. LDS staging is right.
// R4 (FAILED): fewer rounds via tail-pairing -> slightly worse.
// R5 (WIN): constant-sum bx triplets balance per-CU PV load; XCD-affine GEMM.
// R6 (small WIN): launch_bounds(256,3) + hoisted LDS offsets (-1.5us).
// R7: the 3 co-resident blocks run an IDENTICAL 32-round rhythm and launch
//   together -> phase-locked convoy: drains+barriers+stage bursts collide,
//   wall/round ~= sum of 3 serial paths (3800cy) instead of max-pipe (~1300).
//   Fix: s_sleep stagger by CU slot (s = idx>>5) ~512*s cycles at entry; the
//   offset is self-sustaining since round periods match.

typedef __bf16 bf16;
typedef __attribute__((ext_vector_type(4))) __bf16 bf16x4;
typedef __attribute__((ext_vector_type(8))) __bf16 bf16x8;
typedef __attribute__((ext_vector_type(4))) float f32x4;
typedef __attribute__((ext_vector_type(16))) float f32x16;
typedef __attribute__((ext_vector_type(4))) unsigned int uint4v;

#define MFMA16(a,b,c) __builtin_amdgcn_mfma_f32_16x16x32_bf16((a),(b),(c),0,0,0)
#define MFMA32(a,b,c) __builtin_amdgcn_mfma_f32_32x32x16_bf16((a),(b),(c),0,0,0)

typedef const __attribute__((address_space(1))) unsigned int GU32;
typedef __attribute__((address_space(3))) unsigned int LU32;

__device__ __forceinline__ void gll16(const void* gsrc, void* ldst) {
    __builtin_amdgcn_global_load_lds((GU32*)gsrc, (LU32*)ldst, 16, 0, 0);
}

__device__ __forceinline__ unsigned pk_bf16(float lo, float hi) {
    unsigned r;
    asm("v_cvt_pk_bf16_f32 %0, %1, %2" : "=v"(r) : "v"(lo), "v"(hi));
    return r;
}

// v_permlane32_swap_b32: a.hi32lanes <-> b.lo32lanes
__device__ __forceinline__ void plane32swap(unsigned &a, unsigned &b) {
    asm("v_permlane32_swap_b32 %0, %1" : "+v"(a), "+v"(b));
}

__device__ __forceinline__ bf16x8 frag_words(unsigned w0, unsigned w1, unsigned w2, unsigned w3) {
    union { unsigned u[4]; bf16x8 v; } f;
    f.u[0] = w0; f.u[1] = w1; f.u[2] = w2; f.u[3] = w3;
    return f.v;
}

// ------- fp32 -> bf16 streaming convert for q/k/v activations -------
__global__ __launch_bounds__(256) void cvt_qkv(
    const float* __restrict__ q, const float* __restrict__ k, const float* __restrict__ v,
    bf16* __restrict__ Qb, bf16* __restrict__ Kb, bf16* __restrict__ Vb)
{
    const float* src = blockIdx.y == 0 ? q : blockIdx.y == 1 ? k : v;
    bf16* dst = blockIdx.y == 0 ? Qb : blockIdx.y == 1 ? Kb : Vb;
    const size_t base = (size_t)blockIdx.x * 2048 + (size_t)threadIdx.x * 8;
    f32x4 lo = *(const f32x4*)&src[base];
    f32x4 hi = *(const f32x4*)&src[base + 4];
    bf16x8 o;
    for (int j = 0; j < 4; ++j) { o[j] = (bf16)lo[j]; o[4 + j] = (bf16)hi[j]; }
    *(bf16x8*)&dst[base] = o;
}

// ------- weight transpose + cvt: out_bf16[n*768+k] = (bf16)in_f32[k*768+n] -------
struct TArg { const float* in; bf16* out; };

__global__ __launch_bounds__(256) void transpose_w(TArg a0, TArg a1, TArg a2, TArg a3) {
    TArg ta = blockIdx.z == 0 ? a0 : blockIdx.z == 1 ? a1 : blockIdx.z == 2 ? a2 : a3;
    __shared__ bf16 tile[64][72];
    const int bx = blockIdx.x % 12, by = blockIdx.x / 12;
    const int k0 = by * 64, n0 = bx * 64;
    const int tid = threadIdx.x;
    for (int q = 0; q < 2; ++q) {
        int idx = q * 256 + tid;
        int i = idx >> 3, j0 = (idx & 7) * 8;
        const float* src = &ta.in[(size_t)(k0 + i) * 768 + n0 + j0];
        f32x4 lo = *(const f32x4*)&src[0];
        f32x4 hi = *(const f32x4*)&src[4];
        bf16x8 v;
        for (int j = 0; j < 4; ++j) { v[j] = (bf16)lo[j]; v[4 + j] = (bf16)hi[j]; }
        *(bf16x8*)&tile[i][j0] = v;
    }
    __syncthreads();
    for (int q = 0; q < 2; ++q) {
        int idx = q * 256 + tid;
        int n = idx >> 3, j0 = (idx & 7) * 8;
        bf16x8 v;
        for (int jj = 0; jj < 8; ++jj) v[jj] = tile[j0 + jj][n];
        *(bf16x8*)&ta.out[(size_t)(n0 + n) * 768 + k0 + j0] = v;
    }
}

// ------- V slab transpose: Vt[g][d][k] = Vp[g*131072 + k*64 + d] -------
__global__ __launch_bounds__(256) void vtrans(const bf16* __restrict__ Vp, bf16* __restrict__ Vt) {
    __shared__ bf16 tile[64][72];
    const int g = blockIdx.y;
    const int k0 = blockIdx.x * 64;
    const bf16* src = Vp + (size_t)g * 131072;
    bf16* dst = Vt + (size_t)g * 131072;
    const int tid = threadIdx.x;
    for (int q = 0; q < 2; ++q) {
        int idx = q * 256 + tid;
        int r = idx >> 3, c = (idx & 7) * 8;
        *(uint4v*)&tile[r][c] = *(const uint4v*)&src[(size_t)(k0 + r) * 64 + c];
    }
    __syncthreads();
    for (int q = 0; q < 2; ++q) {
        int idx = q * 256 + tid;
        int d = idx >> 3, c = (idx & 7) * 8;
        bf16x8 v;
        for (int j = 0; j < 8; ++j) v[j] = tile[c + j][d];
        *(bf16x8*)&dst[(size_t)d * 2048 + k0 + c] = v;
    }
}

// --- GEMM: C[4096x768] = (A @ Bt^T + bias) * scale.  A is bf16 always.
//     MODE 0: C bf16 (proj);  MODE 1: C fp32 (out)
//     R5: XCD-affine block remap. ---
struct GArg { const bf16* A; const bf16* Bt; const float* bias; void* C; float scale; };

template<int MODE>
__global__ __launch_bounds__(256) void gemm_bt_bias(GArg g0, GArg g1, GArg g2) {
    const int flat = blockIdx.x + 6 * blockIdx.y + 192 * blockIdx.z;
    const int xcd = flat & 7;
    const int idx = flat >> 3;          // z=3: 0..71, z=1: 0..23
    const int mat = idx / 24;
    const int rem = idx % 24;
    const int rloc = rem / 6, colb = rem % 6;
    GArg ga = mat == 0 ? g0 : mat == 1 ? g1 : g2;
    const int K = 768, N = 768;
    __shared__ bf16 As[2][128][64];
    __shared__ bf16 Bs[2][128][64];
    const int tid = threadIdx.x;
    const int lane = tid & 63, wave = tid >> 6;
    const int l15 = lane & 15, lg = lane >> 4;
    const int r0 = (xcd * 4 + rloc) * 128, c0 = colb * 128;
    const int wr = (wave >> 1) * 64, wc = (wave & 1) * 64;
    f32x4 acc[4][4] = {};

    const int grow = wave * 8 + (lane >> 3);
    const int gcol = 8 * ((lane & 7) ^ (lane >> 3));

    auto stage = [&](int kt, int buf) {
        for (int i = 0; i < 4; ++i)
            gll16(&ga.A[(size_t)(r0 + i * 32 + grow) * K + kt + gcol], &As[buf][i * 32 + wave * 8][0]);
        for (int i = 0; i < 4; ++i)
            gll16(&ga.Bt[(size_t)(c0 + i * 32 + grow) * K + kt + gcol], &Bs[buf][i * 32 + wave * 8][0]);
    };

    stage(0, 0);
    __syncthreads();

    for (int c = 0; c < 12; ++c) {
        const int buf = c & 1;
        if (c < 11) stage((c + 1) * 64, buf ^ 1);   // fire-and-forget, drained at barrier
        for (int kk = 0; kk < 2; ++kk) {
            bf16x8 af[4], bfr[4];
            for (int i = 0; i < 4; ++i) {
                int row = wr + i * 16 + l15;
                af[i] = *(const bf16x8*)&As[buf][row][(kk * 32 + lg * 8) ^ ((row & 7) * 8)];
            }
            for (int j = 0; j < 4; ++j) {
                int row = wc + j * 16 + l15;
                bfr[j] = *(const bf16x8*)&Bs[buf][row][(kk * 32 + lg * 8) ^ ((row & 7) * 8)];
            }
            __builtin_amdgcn_s_setprio(1);
            for (int i = 0; i < 4; ++i)
                for (int j = 0; j < 4; ++j)
                    acc[i][j] = MFMA16(af[i], bfr[j], acc[i][j]);
            __builtin_amdgcn_s_setprio(0);
        }
        __syncthreads();
    }
    for (int j = 0; j < 4; ++j) {
        int col = c0 + wc + j * 16 + l15;
        float bv = ga.bias[col];
        for (int i = 0; i < 4; ++i) {
            int row = r0 + wr + i * 16 + lg * 4;
            for (int r = 0; r < 4; ++r) {
                float val = (acc[i][j][r] + bv) * ga.scale;
                if constexpr (MODE == 0)
                    ((bf16*)ga.C)[(size_t)(row + r) * N + col] = (bf16)val;
                else
                    ((float*)ga.C)[(size_t)(row + r) * N + col] = val;
            }
        }
    }
}

// ------- attention v11: v10 + slot stagger (anti-convoy) -------
// Block = 4 waves over 64 q-rows. Wave (wq=w>>1, p=w&1): q rows t0+wq*32..+31,
// k-half p of each 64-chunk. Swapped QK: S-regs q=lane&31, k=(r&3)+8*(r>>2)+4*hi.
// bid mapping: xcd = bid&7 keeps K/V L2-local; constant-sum bx permutations
// across slots. s_sleep(8*s) staggers the 3 co-resident blocks so their
// drain/barrier/stage bursts interleave with each other's compute phases.
__global__ __launch_bounds__(256, 3) void attn_kernel(
    const bf16* __restrict__ Qp, const bf16* __restrict__ Kp,
    const bf16* __restrict__ Vtg, bf16* __restrict__ Ob)
{
    const int bid = blockIdx.x;
    const int xcd = bid & 7;
    const int idx = bid >> 3;            // 0..95
    const int t = idx & 31, s = idx >> 5;
    const int bx = (s == 0) ? (31 - t)
                 : (s == 1) ? ((15 - t) & 31)
                 : (((t << 1) & 31) | (t >> 4));
    const int g = xcd * 3 + s;
    const int t0 = bx * 64;
    const int tid = threadIdx.x, lane = tid & 63, w = tid >> 6;
    const int wq = w >> 1, p = w & 1;
    const int l31 = lane & 31, hi = lane >> 5;

    // anti-convoy stagger: co-resident slots offset ~512*s cycles
    if (s == 1) __builtin_amdgcn_s_sleep(8);
    else if (s == 2) __builtin_amdgcn_s_sleep(16);

    __shared__ __align__(16) char smem[32768];
    // Ks buffer b at smem + b*8192 (elements: b*4096): [64][64] bf16, d-swizzled
    // Vs buffer b at smem + 16384 + b*8192: [64][64] bf16 (V^T: [d][k]), k-swizzled
    bf16* KsE = (bf16*)smem;
    bf16* VsE = (bf16*)(smem + 16384);

    const bf16* Qg = Qp + (size_t)g * 131072;
    const bf16* Kg = Kp + (size_t)g * 131072;
    const bf16* Vg = Vtg + (size_t)g * 131072;   // [64][2048]
    bf16* Og = Ob + (size_t)g * 131072;

    // Q B-frags in registers: col=q=l31, k-dim d = m*16 + hi*8 + j
    const int qrow = t0 + wq * 32 + l31;
    bf16x8 qB[4];
    for (int m = 0; m < 4; ++m)
        qB[m] = *(const bf16x8*)&Qg[(size_t)qrow * 64 + m * 16 + hi * 8];

    // staging: wave stages 16 rows (2 gll of 8 rows), pre-swizzled source col
    const int srow = w * 16 + (lane >> 3);
    const int scol = 8 * ((lane & 7) ^ (lane >> 3));
    auto stageK = [&](int ch, int b2) {
        const bf16* src = &Kg[(size_t)(ch * 64 + srow) * 64 + scol];
        bf16* dst = KsE + b2 * 4096 + w * 16 * 64;
        gll16(src, dst);
        gll16(src + 8 * 64, dst + 8 * 64);
    };
    auto stageV = [&](int ch, int b2) {
        const bf16* src = &Vg[(size_t)srow * 2048 + ch * 64 + scol];
        bf16* dst = VsE + b2 * 4096 + w * 16 * 64;
        gll16(src, dst);
        gll16(src + 8 * 2048, dst + 8 * 64);
    };

    stageK(0, 0);
    stageV(0, 0);

    f32x16 oacc0 = {}, oacc1 = {};
    float dsum = 0.f;
    const int qmax = t0 + wq * 32 + 31;                 // wave's q range top
    const int qmin = t0 + wq * 32;
    const int kofs = p * 32;                            // wave's k-half offset
    const int swz = (l31 & 7) * 8;

    // hoisted per-lane LDS element offsets (loop-invariant; buffer = +4096)
    int koff[4], voff0[2], voff1[2];
    for (int m = 0; m < 4; ++m)
        koff[m] = (kofs + l31) * 64 + ((m * 16 + hi * 8) ^ swz);
    for (int kt = 0; kt < 2; ++kt) {
        const int col = (kofs + kt * 16 + hi * 8) ^ swz;
        voff0[kt] = l31 * 64 + col;
        voff1[kt] = (32 + l31) * 64 + col;
    }

    for (int c = 0; c < 32; ++c) {
        const int boff = (c & 1) * 4096;
        asm volatile("s_waitcnt vmcnt(0)" ::: "memory");
        __builtin_amdgcn_s_barrier();
        __builtin_amdgcn_sched_barrier(0);
        if (c < 31) {
            stageK(c + 1, (c & 1) ^ 1);
            if (c + 1 <= bx) stageV(c + 1, (c & 1) ^ 1);
        }
        __builtin_amdgcn_sched_barrier(0);

        const int kc = c * 64;
        const bool activ = (kc + kofs <= qmax);         // wave-uniform
        const bool fullc = (kc + kofs + 31 <= qmin);    // wave-uniform

        // ---- QK^T: A = K rows (wave's 32-k half), B = Q regs
        f32x16 s2 = {};
        __builtin_amdgcn_s_setprio(1);
        for (int m = 0; m < 4; ++m) {
            bf16x8 kf = *(const bf16x8*)&KsE[boff + koff[m]];
            s2 = MFMA32(kf, qB[m], s2);
        }
        __builtin_amdgcn_s_setprio(0);

        // ---- exp2 (Q pre-scaled by log2e/8) + denominator (UNmasked, tree sum)
        float e[16];
        for (int r = 0; r < 16; ++r) e[r] = __builtin_exp2f(s2[r]);
        {
            float p01 = e[0] + e[1],  p23 = e[2] + e[3];
            float p45 = e[4] + e[5],  p67 = e[6] + e[7];
            float p89 = e[8] + e[9],  pab = e[10] + e[11];
            float pcd = e[12] + e[13], pef = e[14] + e[15];
            float q0 = p01 + p23, q1 = p45 + p67, q2 = p89 + pab, q3 = pcd + pef;
            dsum += (q0 + q1) + (q2 + q3);
        }

        if (activ) {
            if (!fullc) {   // diagonal: tril AFTER softmax
                for (int r = 0; r < 16; ++r) {
                    int kg = kc + kofs + (r & 3) + 8 * (r >> 2) + 4 * hi;
                    if (kg > qrow) e[r] = 0.f;
                }
            }
            // ---- pack P to bf16 + permlane32_swap -> 2 PV A-frags, no LDS
            bf16x8 pf[2];
            {
                unsigned a0 = pk_bf16(e[0], e[1]), a1 = pk_bf16(e[2], e[3]);
                unsigned b0 = pk_bf16(e[4], e[5]), b1 = pk_bf16(e[6], e[7]);
                plane32swap(a0, b0); plane32swap(a1, b1);
                pf[0] = frag_words(a0, a1, b0, b1);
                a0 = pk_bf16(e[8], e[9]);   a1 = pk_bf16(e[10], e[11]);
                b0 = pk_bf16(e[12], e[13]); b1 = pk_bf16(e[14], e[15]);
                plane32swap(a0, b0); plane32swap(a1, b1);
                pf[1] = frag_words(a0, a1, b0, b1);
            }
            // ---- PV: A = P frags, B = V^T tile (col d, row k)
            __builtin_amdgcn_s_setprio(1);
            for (int kt = 0; kt < 2; ++kt) {
                bf16x8 v0 = *(const bf16x8*)&VsE[boff + voff0[kt]];
                bf16x8 v1 = *(const bf16x8*)&VsE[boff + voff1[kt]];
                oacc0 = MFMA32(pf[kt], v0, oacc0);
                oacc1 = MFMA32(pf[kt], v1, oacc1);
            }
            __builtin_amdgcn_s_setprio(0);
        }
    }

    // ---- wave-internal k reduce: lane & lane^32 hold complementary k for q=l31
    dsum += __shfl_xor(dsum, 32);

    // ---- cross-pair reduce via LDS overlay (Ks/Vs regions dead after loop)
    __syncthreads();
    float* Ored = (float*)smem;                 // [pair][q 0-31][d 0-63] = 2 x 8KB
    float* dred = (float*)(smem + 16384);       // [wave][q 0-31] = 512 B
    if (l31 == lane) dred[w * 32 + l31] = dsum; // lanes 0-31 only
    if (p == 1) {
        float* Op = Ored + wq * 2048;
        for (int r = 0; r < 16; ++r) {
            const int qoff = (r & 3) + 8 * (r >> 2) + 4 * hi;
            Op[qoff * 64 + l31]      = oacc0[r];
            Op[qoff * 64 + 32 + l31] = oacc1[r];
        }
    }
    __syncthreads();
    if (p == 0) {
        const float dtot = dsum + dred[(w + 1) * 32 + l31];
        const float rall = 1.0f / dtot;          // valid for q=l31 at every lane
        const float* Op = Ored + wq * 2048;
        for (int r = 0; r < 16; ++r) {
            const int qoff = (r & 3) + 8 * (r >> 2) + 4 * hi;
            const float inv = __shfl(rall, qoff);
            const size_t row = (size_t)(t0 + wq * 32 + qoff) * 64;
            Og[row + l31]      = (bf16)((oacc0[r] + Op[qoff * 64 + l31])      * inv);
            Og[row + 32 + l31] = (bf16)((oacc1[r] + Op[qoff * 64 + 32 + l31]) * inv);
        }
    }
}

// ---------------- host ----------------
extern "C" void kernel_launch(void* const* d_in, const int* in_sizes, int n_in,
                              void* d_out, int out_size, void* d_ws, size_t ws_size,
                              hipStream_t stream) {
    const float* query = (const float*)d_in[0];
    const float* key_  = (const float*)d_in[1];
    const float* value = (const float*)d_in[2];
    const float* Wq = (const float*)d_in[3];
    const float* bq = (const float*)d_in[4];
    const float* Wk = (const float*)d_in[5];
    const float* bk = (const float*)d_in[6];
    const float* Wv = (const float*)d_in[7];
    const float* bv = (const float*)d_in[8];
    const float* Wo = (const float*)d_in[9];
    const float* bo = (const float*)d_in[10];
    float* out = (float*)d_out;

    const size_t MN = (size_t)4096 * 768;
    const size_t WW = (size_t)768 * 768;
    bf16* Qp  = (bf16*)d_ws;
    bf16* Kp  = Qp + MN;
    bf16* Vp  = Kp + MN;
    bf16* Obf = Vp + MN;
    bf16* Vtg = Obf + MN;
    bf16* WtQ = Vtg + MN;
    bf16* WtK = WtQ + WW;
    bf16* WtV = WtK + WW;
    bf16* WtO = WtV + WW;
    bf16* Vb  = WtO + WW;    // +1 MN slab
    // bf16 activation inputs: Qb/Kb alias slabs that are only written later
    // (Obf by attn, Vtg by vtrans) — both dead until after gemm<0> consumes them.
    bf16* Qb  = Obf;
    bf16* Kb  = Vtg;

    cvt_qkv<<<dim3(1536, 3), 256, 0, stream>>>(query, key_, value, Qb, Kb, Vb);

    transpose_w<<<dim3(144, 1, 4), 256, 0, stream>>>(
        TArg{Wq, WtQ}, TArg{Wk, WtK}, TArg{Wv, WtV}, TArg{Wo, WtO});

    // fold log2(e)/sqrt(HD) into Q so attention uses native exp2
    gemm_bt_bias<0><<<dim3(6, 32, 3), 256, 0, stream>>>(
        GArg{Qb, WtQ, bq, Qp, 0.18033688f},
        GArg{Kb, WtK, bk, Kp, 1.0f},
        GArg{Vb, WtV, bv, Vp, 1.0f});

    vtrans<<<dim3(32, 24), 256, 0, stream>>>(Vp, Vtg);

    attn_kernel<<<dim3(768), 256, 0, stream>>>(Qp, Kp, Vtg, Obf);

    gemm_bt_bias<1><<<dim3(6, 32, 1), 256, 0, stream>>>(
        GArg{Obf, WtO, bo, out, 1.0f},
        GArg{Obf, WtO, bo, out, 1.0f},
        GArg{Obf, WtO, bo, out, 1.0f});
}